// Round 3
// baseline (10310.355 us; speedup 1.0000x reference)
//
#include <hip/hip_runtime.h>

constexpr int Bn = 2, Cn = 128, FH = 96, FW = 160, Hh = 384, Wh = 640;
constexpr int HWl = FH * FW;   // 15360
constexpr int NHd = 4, NPt = 9;

#define DEVINL __device__ __forceinline__

template<int ACT> DEVINL float activ(float v) {
  if (ACT == 1) return v >= 0.f ? v : 0.1f * v;                       // leaky relu
  if (ACT == 2) return 0.5f * v * (1.f + erff(v * 0.70710678118654752f)); // exact gelu
  if (ACT == 3) return 1.f / (1.f + expf(-v));                        // sigmoid
  return v;
}

// ---------------------------------------------------------------------------
// Warp feat1/feat2 by (downsampled, scaled) flows; build fused concat + source.
// ---------------------------------------------------------------------------
__global__ __launch_bounds__(256) void k_warp_fuse2(
    const float* __restrict__ feat1, const float* __restrict__ feat2,
    const float* __restrict__ flowf, const float* __restrict__ flowb,
    const float* __restrict__ edge1, const float* __restrict__ edge2,
    float* __restrict__ fused, float* __restrict__ source)
{
  int idx = blockIdx.x * blockDim.x + threadIdx.x;
  if (idx >= Bn * 8 * HWl) return;
  int pix = idx % HWl;
  int cq = (idx / HWl) & 7;
  int b = idx / (HWl * 8);
  int j = pix % FW;
  int i = pix / FW;

  const int y4 = 4 * i + 1, x4 = 4 * j + 1;
  const float* p;
  p = flowf + (size_t)((b * 2 + 0) * Hh + y4) * Wh + x4;
  float fx1 = 0.03125f * (p[0] + p[1] + p[Wh] + p[Wh + 1]);
  p = flowf + (size_t)((b * 2 + 1) * Hh + y4) * Wh + x4;
  float fy1 = 0.03125f * (p[0] + p[1] + p[Wh] + p[Wh + 1]);
  p = flowb + (size_t)((b * 2 + 0) * Hh + y4) * Wh + x4;
  float fx2 = 0.03125f * (p[0] + p[1] + p[Wh] + p[Wh + 1]);
  p = flowb + (size_t)((b * 2 + 1) * Hh + y4) * Wh + x4;
  float fy2 = 0.03125f * (p[0] + p[1] + p[Wh] + p[Wh + 1]);

  float sx1 = fminf(fmaxf((float)j + fx1, 0.f), (float)(FW - 1));
  float sy1 = fminf(fmaxf((float)i + fy1, 0.f), (float)(FH - 1));
  float sx2 = fminf(fmaxf((float)j + fx2, 0.f), (float)(FW - 1));
  float sy2 = fminf(fmaxf((float)i + fy2, 0.f), (float)(FH - 1));

  int x10 = (int)floorf(sx1), y10 = (int)floorf(sy1);
  int x11 = min(x10 + 1, FW - 1), y11 = min(y10 + 1, FH - 1);
  float wx1 = sx1 - (float)x10, wy1 = sy1 - (float)y10;
  int x20 = (int)floorf(sx2), y20 = (int)floorf(sy2);
  int x21 = min(x20 + 1, FW - 1), y21 = min(y20 + 1, FH - 1);
  float wx2 = sx2 - (float)x20, wy2 = sy2 - (float)y20;

  float a00 = (1.f - wx1) * (1.f - wy1), a01 = wx1 * (1.f - wy1);
  float a10 = (1.f - wx1) * wy1,         a11 = wx1 * wy1;
  float c00 = (1.f - wx2) * (1.f - wy2), c01 = wx2 * (1.f - wy2);
  float c10 = (1.f - wx2) * wy2,         c11 = wx2 * wy2;
  int o00 = y10 * FW + x10, o01 = y10 * FW + x11, o10 = y11 * FW + x10, o11 = y11 * FW + x11;
  int q00 = y20 * FW + x20, q01 = y20 * FW + x21, q10 = y21 * FW + x20, q11 = y21 * FW + x21;

  if (cq == 0) {
    p = edge1 + (size_t)(b * Hh + y4) * Wh + x4;
    fused[(size_t)(b * 259 + 256) * HWl + pix] = 0.25f * (p[0] + p[1] + p[Wh] + p[Wh + 1]);
    p = edge2 + (size_t)(b * Hh + y4) * Wh + x4;
    fused[(size_t)(b * 259 + 257) * HWl + pix] = 0.25f * (p[0] + p[1] + p[Wh] + p[Wh + 1]);
    fused[(size_t)(b * 259 + 258) * HWl + pix] = 0.5f;  // tmap = T
  }

  int c0 = cq * 16;
  for (int c = c0; c < c0 + 16; ++c) {
    const float* f1 = feat1 + (size_t)(b * Cn + c) * HWl;
    const float* f2 = feat2 + (size_t)(b * Cn + c) * HWl;
    float v1 = f1[o00] * a00 + f1[o01] * a01 + f1[o10] * a10 + f1[o11] * a11;
    float v2 = f2[q00] * c00 + f2[q01] * c01 + f2[q10] * c10 + f2[q11] * c11;
    fused[(size_t)(b * 259 + c) * HWl + pix] = v1;
    fused[(size_t)(b * 259 + 128 + c) * HWl + pix] = v2;
    source[(size_t)(b * Cn + c) * HWl + pix] = 0.5f * (v1 + v2);
  }
}

// ---------------------------------------------------------------------------
// LDS-tiled 3x3 conv. Block = 256 thr = 64 px-groups(4px) x 4 waves(COT=8 co).
// Output tile: 8 rows x 32 cols x 32 co. Per cin-slice (CS=8) the halo tile
// (10 x 34) is staged in LDS once -> input reuse across all 32 co in-block.
// UP=1: input is the 4x bilinear upsample of `in` (B,Cin,96,160), computed
// on the fly during staging (Htot/W refer to upsampled space).
// Windows: in buffer holds global rows [in_r0, +in_rows) (ignored for UP);
// out holds [out_r0, +out_rows); computes rows [ogr0, ogr1).
// Requires: W%32==0, Cout%32==0, 32 divides cout_g.
// ---------------------------------------------------------------------------
template<int ACT, int UP>
__global__ __launch_bounds__(256) void k_conv3x3_lds(
    const float* __restrict__ in, const float* __restrict__ wt,
    const float* __restrict__ bias, float* __restrict__ out,
    int Cin, int Cout, int W, int Htot,
    int in_r0, int in_rows, int out_r0, int out_rows,
    int ogr0, int ogr1, int cin_g, int cout_g)
{
  constexpr int TR = 8, TC = 32, CS = 8, COT = 8;
  __shared__ float sIn[CS * 10 * 36];   // [ch][row(10)][col pad 36]; 11.5 KB

  int tid = threadIdx.x;
  int wv = __builtin_amdgcn_readfirstlane(tid >> 6);   // wave id 0..3 (SGPR)
  int pxg = tid & 63;
  int prow = pxg >> 3;            // 0..7
  int pcol4 = (pxg & 7) << 2;     // 0..28
  int colTiles = W / TC;
  int tileC = blockIdx.x % colTiles;
  int tileR = blockIdx.x / colTiles;
  int cotiles = Cout >> 5;        // Cout/32
  int cog = blockIdx.y % cotiles;
  int b = blockIdx.y / cotiles;
  int co0 = cog * 32 + wv * COT;
  int cib = ((cog * 32) / cout_g) * cin_g;
  int r = ogr0 + tileR * TR + prow;
  int j0 = tileC * TC + pcol4;
  int rbase = ogr0 + tileR * TR - 1;
  int cbase = tileC * TC;

  float acc[COT][4];
#pragma unroll
  for (int cc = 0; cc < COT; ++cc) {
    float bv = bias[co0 + cc];
    acc[cc][0] = bv; acc[cc][1] = bv; acc[cc][2] = bv; acc[cc][3] = bv;
  }
  int lidx = (pcol4 == 0) ? 33 : pcol4 - 1;
  int ridx = (pcol4 == 28) ? 32 : pcol4 + 4;

  int slices = (cin_g + CS - 1) / CS;
  for (int sl = 0; sl < slices; ++sl) {
    int cs0 = sl * CS;
    int sn = min(CS, cin_g - cs0);
    // ---- stage halo tile for CS channels ----
    for (int e = tid; e < CS * 10 * 36; e += 256) {
      int ch = e / 360;
      int rem = e - ch * 360;
      int lr = rem / 36;
      int lc = rem - lr * 36;
      if (lc >= 34) continue;
      int gcol = cbase + (lc < 32 ? lc : (lc == 32 ? 32 : -1));
      int grow = rbase + lr;
      float v = 0.f;
      if (ch < sn) {
        if (UP) {
          if (grow >= 0 && grow < Htot && gcol >= 0 && gcol < W) {
            float uy = ((float)grow + 0.5f) * 0.25f - 0.5f;
            uy = fminf(fmaxf(uy, 0.f), (float)(FH - 1));
            int y0 = (int)floorf(uy);
            int y1 = min(y0 + 1, FH - 1);
            float fy = uy - (float)y0;
            float ux = ((float)gcol + 0.5f) * 0.25f - 0.5f;
            ux = fminf(fmaxf(ux, 0.f), (float)(FW - 1));
            int x0 = (int)floorf(ux);
            int x1 = min(x0 + 1, FW - 1);
            float fx = ux - (float)x0;
            const float* xb = in + (size_t)(b * Cin + cib + cs0 + ch) * HWl;
            float t0 = xb[y0 * FW + x0] * (1.f - fx) + xb[y0 * FW + x1] * fx;
            float t1 = xb[y1 * FW + x0] * (1.f - fx) + xb[y1 * FW + x1] * fx;
            v = t0 * (1.f - fy) + t1 * fy;
          }
        } else {
          if (grow >= in_r0 && grow < in_r0 + in_rows && gcol >= 0 && gcol < W)
            v = in[((size_t)(b * Cin + cib + cs0 + ch) * in_rows + (grow - in_r0)) * W + gcol];
        }
      }
      sIn[e] = v;
    }
    __syncthreads();
    // ---- compute ----
    const float* wb0 = wt + ((size_t)co0 * cin_g + cs0) * 9;
    if (sn == CS) {
#pragma unroll
      for (int cs = 0; cs < CS; ++cs) {
        float4 m[3]; float lf[3], rg[3];
#pragma unroll
        for (int dy = 0; dy < 3; ++dy) {
          const float* rowp = &sIn[(cs * 10 + prow + dy) * 36];
          m[dy] = *reinterpret_cast<const float4*>(rowp + pcol4);
          lf[dy] = rowp[lidx];
          rg[dy] = rowp[ridx];
        }
#pragma unroll
        for (int cc = 0; cc < COT; ++cc) {
          const float* wp = wb0 + ((size_t)cc * cin_g + cs) * 9;
#pragma unroll
          for (int dy = 0; dy < 3; ++dy) {
            float wa = wp[dy * 3], wbv = wp[dy * 3 + 1], wc = wp[dy * 3 + 2];
            acc[cc][0] += wa * lf[dy]   + wbv * m[dy].x + wc * m[dy].y;
            acc[cc][1] += wa * m[dy].x  + wbv * m[dy].y + wc * m[dy].z;
            acc[cc][2] += wa * m[dy].y  + wbv * m[dy].z + wc * m[dy].w;
            acc[cc][3] += wa * m[dy].z  + wbv * m[dy].w + wc * rg[dy];
          }
        }
      }
    } else {
      for (int cs = 0; cs < sn; ++cs) {
        float4 m[3]; float lf[3], rg[3];
#pragma unroll
        for (int dy = 0; dy < 3; ++dy) {
          const float* rowp = &sIn[(cs * 10 + prow + dy) * 36];
          m[dy] = *reinterpret_cast<const float4*>(rowp + pcol4);
          lf[dy] = rowp[lidx];
          rg[dy] = rowp[ridx];
        }
#pragma unroll
        for (int cc = 0; cc < COT; ++cc) {
          const float* wp = wb0 + ((size_t)cc * cin_g + cs) * 9;
#pragma unroll
          for (int dy = 0; dy < 3; ++dy) {
            float wa = wp[dy * 3], wbv = wp[dy * 3 + 1], wc = wp[dy * 3 + 2];
            acc[cc][0] += wa * lf[dy]   + wbv * m[dy].x + wc * m[dy].y;
            acc[cc][1] += wa * m[dy].x  + wbv * m[dy].y + wc * m[dy].z;
            acc[cc][2] += wa * m[dy].y  + wbv * m[dy].z + wc * m[dy].w;
            acc[cc][3] += wa * m[dy].z  + wbv * m[dy].w + wc * rg[dy];
          }
        }
      }
    }
    __syncthreads();
  }

  if (r < ogr1) {
#pragma unroll
    for (int cc = 0; cc < COT; ++cc) {
      float4 res;
      res.x = activ<ACT>(acc[cc][0]); res.y = activ<ACT>(acc[cc][1]);
      res.z = activ<ACT>(acc[cc][2]); res.w = activ<ACT>(acc[cc][3]);
      float* op = out + ((size_t)(b * Cout + co0 + cc) * out_rows + (r - out_r0)) * W + j0;
      *reinterpret_cast<float4*>(op) = res;
    }
  }
}

// ---------------------------------------------------------------------------
// Direct 3x3 conv (kept for tiny dec2: Cout=3). COT co per thread, 4 px.
// ---------------------------------------------------------------------------
template<int ACT, int COT>
__global__ __launch_bounds__(256) void k_conv3x3b(
    const float* __restrict__ in, const float* __restrict__ wt,
    const float* __restrict__ bias, float* __restrict__ out,
    int Cin, int Cout, int W, int Htot,
    int in_r0, int in_rows, int out_r0, int out_rows,
    int ogr0, int ogr1, int cin_g, int cout_g)
{
  int JQ = W >> 2;
  int nrows = ogr1 - ogr0;
  int per = nrows * JQ;
  int idx = blockIdx.x * blockDim.x + threadIdx.x;
  if (idx >= per) return;
  int cotiles = Cout / COT;
  int cot = blockIdx.y % cotiles;
  int b = blockIdx.y / cotiles;
  int co0 = cot * COT;
  int q = idx % JQ;
  int r = idx / JQ + ogr0;
  int j0 = q << 2;
  bool has_l = (j0 > 0), has_r = (j0 + 4 < W);

  float acc[COT][4];
#pragma unroll
  for (int cc = 0; cc < COT; ++cc) {
    float bv = bias[co0 + cc];
    acc[cc][0] = bv; acc[cc][1] = bv; acc[cc][2] = bv; acc[cc][3] = bv;
  }
  int cib = (co0 / cout_g) * cin_g;
  const float* wb0 = wt + (size_t)co0 * cin_g * 9;

  for (int cl = 0; cl < cin_g; ++cl) {
    float4 m[3]; float v0[3], v5[3];
    const float* ibase = in + (size_t)((b * Cin + cib + cl) * in_rows - in_r0) * W;
#pragma unroll
    for (int dy = 0; dy < 3; ++dy) {
      int gr = r + dy - 1;
      if (gr >= 0 && gr < Htot) {
        const float* ip = ibase + (size_t)gr * W;
        m[dy] = *reinterpret_cast<const float4*>(ip + j0);
        v0[dy] = has_l ? ip[j0 - 1] : 0.f;
        v5[dy] = has_r ? ip[j0 + 4] : 0.f;
      } else {
        m[dy] = make_float4(0.f, 0.f, 0.f, 0.f); v0[dy] = 0.f; v5[dy] = 0.f;
      }
    }
#pragma unroll
    for (int cc = 0; cc < COT; ++cc) {
      const float* wp = wb0 + ((size_t)cc * cin_g + cl) * 9;
#pragma unroll
      for (int dy = 0; dy < 3; ++dy) {
        float wa = wp[dy * 3], wb = wp[dy * 3 + 1], wc = wp[dy * 3 + 2];
        acc[cc][0] += wa * v0[dy]   + wb * m[dy].x + wc * m[dy].y;
        acc[cc][1] += wa * m[dy].x  + wb * m[dy].y + wc * m[dy].z;
        acc[cc][2] += wa * m[dy].y  + wb * m[dy].z + wc * m[dy].w;
        acc[cc][3] += wa * m[dy].z  + wb * m[dy].w + wc * v5[dy];
      }
    }
  }
#pragma unroll
  for (int cc = 0; cc < COT; ++cc) {
    float4 res;
    res.x = activ<ACT>(acc[cc][0]); res.y = activ<ACT>(acc[cc][1]);
    res.z = activ<ACT>(acc[cc][2]); res.w = activ<ACT>(acc[cc][3]);
    float* op = out + ((size_t)(b * Cout + co0 + cc) * out_rows + (r - out_r0)) * W + j0;
    *reinterpret_cast<float4*>(op) = res;
  }
}

// ---------------------------------------------------------------------------
// 1x1 conv, COT output channels per thread; optional residual add (RES).
// ---------------------------------------------------------------------------
template<int ACT, int RES, int COT>
__global__ __launch_bounds__(256) void k_conv1x1b(
    const float* __restrict__ in, const float* __restrict__ wt,
    const float* __restrict__ bias, float* __restrict__ out,
    int Cin, int Cout, int HW)
{
  int NQ = HW >> 2;
  int idx = blockIdx.x * blockDim.x + threadIdx.x;
  if (idx >= NQ) return;
  int cotiles = Cout / COT;
  int cot = blockIdx.y % cotiles;
  int b = blockIdx.y / cotiles;
  int co0 = cot * COT;
  int j0 = idx << 2;

  float acc[COT][4];
#pragma unroll
  for (int cc = 0; cc < COT; ++cc) {
    float bv = bias[co0 + cc];
    acc[cc][0] = bv; acc[cc][1] = bv; acc[cc][2] = bv; acc[cc][3] = bv;
  }
  const float* ip = in + (size_t)b * Cin * HW + j0;
  for (int ci = 0; ci < Cin; ++ci) {
    float4 v = *reinterpret_cast<const float4*>(ip + (size_t)ci * HW);
#pragma unroll
    for (int cc = 0; cc < COT; ++cc) {
      float wv = wt[(size_t)(co0 + cc) * Cin + ci];
      acc[cc][0] += wv * v.x; acc[cc][1] += wv * v.y;
      acc[cc][2] += wv * v.z; acc[cc][3] += wv * v.w;
    }
  }
#pragma unroll
  for (int cc = 0; cc < COT; ++cc) {
    float4 res;
    res.x = activ<ACT>(acc[cc][0]); res.y = activ<ACT>(acc[cc][1]);
    res.z = activ<ACT>(acc[cc][2]); res.w = activ<ACT>(acc[cc][3]);
    float* op = out + (size_t)(b * Cout + co0 + cc) * HW + j0;
    if (RES) {
      float4 pv = *reinterpret_cast<const float4*>(op);
      res.x += pv.x; res.y += pv.y; res.z += pv.z; res.w += pv.w;
    }
    *reinterpret_cast<float4*>(op) = res;
  }
}

// ---------------------------------------------------------------------------
// GroupNorm two-stage.
// ---------------------------------------------------------------------------
__global__ __launch_bounds__(256) void k_gn_part(
    const float* __restrict__ x, float* __restrict__ part)
{
  int s = blockIdx.x & 7;
  int g = (blockIdx.x >> 3) & 7;
  int b = blockIdx.x >> 6;
  const float* base = x + (size_t)(b * Cn + g * 16) * HWl;
  const int chunk = 16 * HWl / 8;   // 30720
  float sum = 0.f, ss = 0.f;
  for (int t = s * chunk + threadIdx.x; t < (s + 1) * chunk; t += 256) {
    float v = base[t];
    sum += v; ss += v * v;
  }
  __shared__ float sh1[256], sh2[256];
  sh1[threadIdx.x] = sum; sh2[threadIdx.x] = ss;
  __syncthreads();
  for (int st = 128; st > 0; st >>= 1) {
    if (threadIdx.x < st) {
      sh1[threadIdx.x] += sh1[threadIdx.x + st];
      sh2[threadIdx.x] += sh2[threadIdx.x + st];
    }
    __syncthreads();
  }
  if (threadIdx.x == 0) {
    part[blockIdx.x * 2] = sh1[0];
    part[blockIdx.x * 2 + 1] = sh2[0];
  }
}

__global__ __launch_bounds__(256) void k_gn_apply(
    const float* __restrict__ x, const float* __restrict__ gw,
    const float* __restrict__ gb, const float* __restrict__ part,
    float* __restrict__ q)
{
  int idx = blockIdx.x * blockDim.x + threadIdx.x;
  int total4 = Bn * Cn * HWl / 4;
  if (idx >= total4) return;
  int e = idx << 2;
  int c = (e / HWl) % Cn;
  int b = e / (HWl * Cn);
  int g = c >> 4;
  const float* pp = part + (size_t)((b * 8 + g) * 8) * 2;
  float sum = 0.f, ss = 0.f;
#pragma unroll
  for (int s = 0; s < 8; ++s) { sum += pp[s * 2]; ss += pp[s * 2 + 1]; }
  const float n = 16.f * HWl;
  float mean = sum / n;
  float var = ss / n - mean * mean;
  float inv = rsqrtf(var + 1e-5f);
  float ga = gw[c] * inv;
  float bb = gb[c];
  float4 v = *reinterpret_cast<const float4*>(x + e);
  float4 r;
  r.x = (v.x - mean) * ga + bb; r.y = (v.y - mean) * ga + bb;
  r.z = (v.z - mean) * ga + bb; r.w = (v.w - mean) * ga + bb;
  *reinterpret_cast<float4*>(q + e) = r;
}

// softmax over the NP=9 points
__global__ __launch_bounds__(256) void k_softmax9(float* __restrict__ a)
{
  int total = Bn * NHd * HWl;
  int idx = blockIdx.x * blockDim.x + threadIdx.x;
  if (idx >= total) return;
  int pix = idx % HWl;
  int head = (idx / HWl) & 3;
  int b = idx / (HWl * NHd);
  float* base = a + (size_t)(b * NHd * NPt + head * NPt) * HWl + pix;
  float v[9];
  float m = -1e30f;
#pragma unroll
  for (int p0 = 0; p0 < 9; ++p0) { v[p0] = base[p0 * HWl]; m = fmaxf(m, v[p0]); }
  float s = 0.f;
#pragma unroll
  for (int p0 = 0; p0 < 9; ++p0) { v[p0] = expf(v[p0] - m); s += v[p0]; }
  float inv = 1.f / s;
#pragma unroll
  for (int p0 = 0; p0 < 9; ++p0) base[p0 * HWl] = v[p0] * inv;
}

// Transpose vals (B,128,HW) -> (B,4head,HW,32ch)
__global__ __launch_bounds__(256) void k_tr32(
    const float* __restrict__ v, float* __restrict__ vt)
{
  int idx = blockIdx.x * blockDim.x + threadIdx.x;
  if (idx >= Bn * NHd * HWl) return;
  int pix = idx % HWl;
  int head = (idx / HWl) & 3;
  int b = idx / (HWl * NHd);
  const float* src = v + (size_t)(b * Cn + head * 32) * HWl + pix;
  float tmp[32];
#pragma unroll
  for (int c = 0; c < 32; ++c) tmp[c] = src[(size_t)c * HWl];
  float* dst = vt + ((size_t)(b * NHd + head) * HWl + pix) * 32;
#pragma unroll
  for (int k = 0; k < 8; ++k) {
    float4 o; o.x = tmp[k*4]; o.y = tmp[k*4+1]; o.z = tmp[k*4+2]; o.w = tmp[k*4+3];
    *reinterpret_cast<float4*>(dst + k * 4) = o;
  }
}

// ---------------------------------------------------------------------------
// Deformable sampling: one thread per (b,head,pixel), all 32 head-channels.
// ---------------------------------------------------------------------------
__global__ __launch_bounds__(256) void k_deform2(
    const float* __restrict__ vals_t, const float* __restrict__ off,
    const float* __restrict__ attn, float* __restrict__ outa)
{
  int idx = blockIdx.x * blockDim.x + threadIdx.x;
  if (idx >= Bn * NHd * HWl) return;
  int pix = idx % HWl;
  int head = (idx / HWl) & 3;
  int b = idx / (HWl * NHd);
  int j = pix % FW, i = pix / FW;

  const float kx = (float)FW / (float)(FW - 1);
  const float ky = (float)FH / (float)(FH - 1);
  const float* vb = vals_t + (size_t)(b * NHd + head) * HWl * 32;
  const float* ab = attn + ((size_t)b * 36 + head * 9) * HWl + pix;
  const float* ob = off + ((size_t)b * 72 + head * 18) * HWl + pix;

  float4 acc[8];
#pragma unroll
  for (int k = 0; k < 8; ++k) acc[k] = make_float4(0.f, 0.f, 0.f, 0.f);

#pragma unroll
  for (int p0 = 0; p0 < 9; ++p0) {
    float ox = ob[(size_t)(p0 * 2) * HWl];
    float oy = ob[(size_t)(p0 * 2 + 1) * HWl];
    float aw = ab[(size_t)p0 * HWl];
    float xf = ((float)j + ox) * kx - 0.5f;
    float yf = ((float)i + oy) * ky - 0.5f;
    xf = fminf(fmaxf(xf, 0.f), (float)(FW - 1));
    yf = fminf(fmaxf(yf, 0.f), (float)(FH - 1));
    int x0 = (int)floorf(xf), y0 = (int)floorf(yf);
    int x1 = min(x0 + 1, FW - 1), y1 = min(y0 + 1, FH - 1);
    float fx = xf - (float)x0, fy = yf - (float)y0;
    float w00 = aw * (1.f - fx) * (1.f - fy);
    float w01 = aw * fx * (1.f - fy);
    float w10 = aw * (1.f - fx) * fy;
    float w11 = aw * fx * fy;
    const float4* c00 = reinterpret_cast<const float4*>(vb + (size_t)(y0 * FW + x0) * 32);
    const float4* c01 = reinterpret_cast<const float4*>(vb + (size_t)(y0 * FW + x1) * 32);
    const float4* c10 = reinterpret_cast<const float4*>(vb + (size_t)(y1 * FW + x0) * 32);
    const float4* c11 = reinterpret_cast<const float4*>(vb + (size_t)(y1 * FW + x1) * 32);
#pragma unroll
    for (int k = 0; k < 8; ++k) {
      float4 a = c00[k], bb = c01[k], cc = c10[k], dd = c11[k];
      acc[k].x += w00 * a.x + w01 * bb.x + w10 * cc.x + w11 * dd.x;
      acc[k].y += w00 * a.y + w01 * bb.y + w10 * cc.y + w11 * dd.y;
      acc[k].z += w00 * a.z + w01 * bb.z + w10 * cc.z + w11 * dd.z;
      acc[k].w += w00 * a.w + w01 * bb.w + w10 * cc.w + w11 * dd.w;
    }
  }
  float* op = outa + (size_t)(b * Cn + head * 32) * HWl + pix;
#pragma unroll
  for (int k = 0; k < 8; ++k) {
    op[(size_t)(k * 4 + 0) * HWl] = acc[k].x;
    op[(size_t)(k * 4 + 1) * HWl] = acc[k].y;
    op[(size_t)(k * 4 + 2) * HWl] = acc[k].z;
    op[(size_t)(k * 4 + 3) * HWl] = acc[k].w;
  }
}

// ---------------------------------------------------------------------------
extern "C" void kernel_launch(void* const* d_in, const int* in_sizes, int n_in,
                              void* d_out, int out_size, void* d_ws, size_t ws_size,
                              hipStream_t stream) {
  (void)in_sizes; (void)n_in; (void)out_size; (void)ws_size;
  const float* feat1  = (const float*)d_in[0];
  const float* feat2  = (const float*)d_in[1];
  const float* flowf  = (const float*)d_in[2];
  const float* flowb  = (const float*)d_in[3];
  const float* edge1  = (const float*)d_in[4];
  const float* edge2  = (const float*)d_in[5];
  const float* fuse_w0 = (const float*)d_in[6];
  const float* fuse_b0 = (const float*)d_in[7];
  const float* fuse_w1 = (const float*)d_in[8];
  const float* fuse_b1 = (const float*)d_in[9];
  const float* gn_g   = (const float*)d_in[10];
  const float* gn_b   = (const float*)d_in[11];
  const float* off_w0 = (const float*)d_in[12];
  const float* off_b0 = (const float*)d_in[13];
  const float* off_w1 = (const float*)d_in[14];
  const float* off_b1 = (const float*)d_in[15];
  const float* aw_w0  = (const float*)d_in[16];
  const float* aw_b0  = (const float*)d_in[17];
  const float* aw_w1  = (const float*)d_in[18];
  const float* aw_b1  = (const float*)d_in[19];
  const float* val_w  = (const float*)d_in[20];
  const float* val_b  = (const float*)d_in[21];
  const float* out_w  = (const float*)d_in[22];
  const float* out_b  = (const float*)d_in[23];
  const float* ffn_w0 = (const float*)d_in[24];
  const float* ffn_b0 = (const float*)d_in[25];
  const float* ffn_w1 = (const float*)d_in[26];
  const float* ffn_b1 = (const float*)d_in[27];
  const float* dec_w0 = (const float*)d_in[28];
  const float* dec_b0 = (const float*)d_in[29];
  const float* dec_w1 = (const float*)d_in[30];
  const float* dec_b1 = (const float*)d_in[31];
  const float* dec_w2 = (const float*)d_in[32];
  const float* dec_b2 = (const float*)d_in[33];
  float* out = (float*)d_out;
  float* ws = (float*)d_ws;

  // Workspace layout (floats), ~108 MB total (as R2, which passed).
  float* xbuf   = ws;                                   // 2*128*HWl
  float* pool   = ws + (size_t)2 * Cn * HWl;
  float* fused  = pool;                                 // 2*259*HWl
  float* source = fused  + (size_t)2 * 259 * HWl;       // 2*128*HWl
  float* tmp1   = source + (size_t)2 * Cn * HWl;        // 2*128*HWl
  float* offb   = tmp1   + (size_t)2 * Cn * HWl;        // 2*72*HWl
  float* attnb  = offb   + (size_t)2 * 72 * HWl;        // 2*36*HWl
  float* valsb  = attnb  + (size_t)2 * 36 * HWl;        // 2*128*HWl
  // Aliases (lifetimes checked):
  float* t_off    = fused;                              // dead after off-1x1
  float* t_aw     = fused + (size_t)2 * Cn * HWl;       // dead after aw-1x1
  float* qb       = tmp1;
  float* out_attn = source;                             // source dead after vals conv
  float* vals_t   = fused;                              // after t_off dead; dead after deform
  float* ffn_t    = fused;                              // after vals_t dead
  float* gnws     = offb;                               // offb written later (step 6)
  // Decoder (96-row chunks, upsample fused into dec0 -> no bufU):
  float* bufA = pool;                                   // <= 2*64*100*640 = 8.19M floats
  float* bufB = bufA + (size_t)2 * 64 * 100 * 640;      // <= 2*32*98*640  = 4.01M floats

  dim3 blk(256);
  auto grd = [](long n) { return dim3((unsigned)((n + 255) / 256)); };
  auto g2 = [](long nx, int ny) { return dim3((unsigned)((nx + 255) / 256), (unsigned)ny); };
  const int NQl = HWl / 4;  // 3840

  // 1. warp + concat + source
  k_warp_fuse2<<<grd(2L * 8 * HWl), blk, 0, stream>>>(feat1, feat2, flowf, flowb,
                                                      edge1, edge2, fused, source);
  // 2. fuse conv0 (259->128) + lrelu.  tiles: 12 row x 5 col; grid.y = 2b*4cog
  dim3 gl(60, 8);
  k_conv3x3_lds<1, 0><<<gl, blk, 0, stream>>>(fused, fuse_w0, fuse_b0, tmp1,
      259, 128, FW, FH, 0, FH, 0, FH, 0, FH, 259, 128);
  // 3. fuse conv1 (128->128) + lrelu -> xbuf
  k_conv3x3_lds<1, 0><<<gl, blk, 0, stream>>>(tmp1, fuse_w1, fuse_b1, xbuf,
      128, 128, FW, FH, 0, FH, 0, FH, 0, FH, 128, 128);
  // 4. group norm -> qb
  k_gn_part<<<dim3(128), blk, 0, stream>>>(xbuf, gnws);
  k_gn_apply<<<grd(2L * Cn * HWl / 4), blk, 0, stream>>>(xbuf, gn_g, gn_b, gnws, qb);
  // 5-6. offsets: grouped 3x3 + lrelu, then 1x1 -> offb (72ch)
  k_conv3x3_lds<1, 0><<<gl, blk, 0, stream>>>(qb, off_w0, off_b0, t_off,
      128, 128, FW, FH, 0, FH, 0, FH, 0, FH, 32, 32);
  k_conv1x1b<0, 0, 8><<<g2(NQl, 2 * 9), blk, 0, stream>>>(t_off, off_w1, off_b1, offb,
      128, 72, HWl);
  // 7-8. attention weights: grouped 3x3 + lrelu, 1x1 -> 36ch, softmax
  k_conv3x3_lds<1, 0><<<gl, blk, 0, stream>>>(qb, aw_w0, aw_b0, t_aw,
      128, 128, FW, FH, 0, FH, 0, FH, 0, FH, 32, 32);
  k_conv1x1b<0, 0, 4><<<g2(NQl, 2 * 9), blk, 0, stream>>>(t_aw, aw_w1, aw_b1, attnb,
      128, 36, HWl);
  k_softmax9<<<grd(2L * NHd * HWl), blk, 0, stream>>>(attnb);
  // 9. vals = 1x1(source); transpose to (B,4,HW,32)
  k_conv1x1b<0, 0, 8><<<g2(NQl, 2 * 16), blk, 0, stream>>>(source, val_w, val_b, valsb,
      128, 128, HWl);
  k_tr32<<<grd(2L * NHd * HWl), blk, 0, stream>>>(valsb, vals_t);
  // 10. deformable sampling + weighted sum -> out_attn (NCHW)
  k_deform2<<<grd(2L * NHd * HWl), blk, 0, stream>>>(vals_t, offb, attnb, out_attn);
  // 11. xbuf += 1x1(out_attn)
  k_conv1x1b<0, 1, 8><<<g2(NQl, 2 * 16), blk, 0, stream>>>(out_attn, out_w, out_b, xbuf,
      128, 128, HWl);
  // 12-13. FFN: 1x1 -> gelu -> 1x1, residual
  k_conv1x1b<2, 0, 8><<<g2(NQl, 2 * 32), blk, 0, stream>>>(xbuf, ffn_w0, ffn_b0, ffn_t,
      128, 256, HWl);
  k_conv1x1b<0, 1, 8><<<g2(NQl, 2 * 16), blk, 0, stream>>>(ffn_t, ffn_w1, ffn_b1, xbuf,
      256, 128, HWl);

  // 14. decoder in 4 row-chunks of 96; upsample fused into dec0's LDS staging
  for (int c0 = 0; c0 < Hh; c0 += 96) {
    int c1 = c0 + 96;
    int a0 = c0 - 2 > 0 ? c0 - 2 : 0;
    int a1 = c1 + 2 < Hh ? c1 + 2 : Hh;
    int b0 = c0 - 1 > 0 ? c0 - 1 : 0;
    int b1 = c1 + 1 < Hh ? c1 + 1 : Hh;
    int ar = a1 - a0, br = b1 - b0;
    // dec0: 128->64 on upsampled grid, rows [a0,a1) -> bufA
    dim3 gd0(20 * ((ar + 7) / 8), 2 * 2);
    k_conv3x3_lds<1, 1><<<gd0, blk, 0, stream>>>(xbuf, dec_w0, dec_b0, bufA,
        128, 64, Wh, Hh, 0, 0, a0, ar, a0, a1, 128, 64);
    // dec1: 64->32, rows [b0,b1) -> bufB
    dim3 gd1(20 * ((br + 7) / 8), 2 * 1);
    k_conv3x3_lds<1, 0><<<gd1, blk, 0, stream>>>(bufA, dec_w1, dec_b1, bufB,
        64, 32, Wh, Hh, a0, ar, b0, br, b0, b1, 64, 32);
    // dec2: 32->3 + sigmoid, rows [c0,c1) -> out
    k_conv3x3b<3, 3><<<g2(96L * 160, 2), blk, 0, stream>>>(bufB, dec_w2, dec_b2, out,
        32, 3, Wh, Hh, b0, br, 0, Hh, c0, c1, 32, 3);
  }
}

// Round 4
// 625.030 us; speedup vs baseline: 16.4958x; 16.4958x over previous
//
#include <hip/hip_runtime.h>

typedef _Float16 f16;
typedef _Float16 f16x8 __attribute__((ext_vector_type(8)));
typedef float f32x4 __attribute__((ext_vector_type(4)));

constexpr int Bn = 2, Cn = 128, FH = 96, FW = 160, Hh = 384, Wh = 640;
constexpr int HWl = FH * FW;   // 15360
constexpr int NHd = 4, NPt = 9;

#define DEVINL __device__ __forceinline__

DEVINL f32x4 zero4() { f32x4 z; z[0] = 0.f; z[1] = 0.f; z[2] = 0.f; z[3] = 0.f; return z; }
DEVINL f16x8 zero8() {
  f16x8 z;
#pragma unroll
  for (int j = 0; j < 8; ++j) z[j] = (f16)0.f;
  return z;
}

template<int ACT> DEVINL float activ(float v) {
  if (ACT == 1) return v >= 0.f ? v : 0.1f * v;                           // leaky relu
  if (ACT == 2) return 0.5f * v * (1.f + erff(v * 0.70710678118654752f)); // exact gelu
  if (ACT == 3) return 1.f / (1.f + expf(-v));                            // sigmoid
  return v;
}

// ---------------------------------------------------------------------------
// Weight prep, 3x3: orig f32 [Cout][cin_g][3][3] -> f16 frag layout
// [tap][ks][cf][lane][8] with k-convention k = (lane>>4)*8 + j (matches A).
// Grouped convs are zero-padded to full Cin (band = (co/cout_g)*cin_g).
// ---------------------------------------------------------------------------
__global__ __launch_bounds__(256) void k_wprep3(
    const float* __restrict__ w, f16* __restrict__ wf,
    int Cout, int cin_g, int cout_g, int KS, int CoF)
{
  int idx = blockIdx.x * blockDim.x + threadIdx.x;
  int total = 9 * KS * CoF * 64;
  if (idx >= total) return;
  int lane = idx & 63;
  int rest = idx >> 6;
  int cf = rest % CoF;
  int rest2 = rest / CoF;
  int ks = rest2 % KS;
  int tap = rest2 / KS;
  int co = cf * 16 + (lane & 15);
  f16x8 v = zero8();
#pragma unroll
  for (int j = 0; j < 8; ++j) {
    int kl = (lane >> 4) * 8 + j;
    int cip = ks * 32 + kl;
    int cil = cip - (co / cout_g) * cin_g;
    float x = 0.f;
    if (co < Cout && cil >= 0 && cil < cin_g)
      x = w[((size_t)co * cin_g + cil) * 9 + tap];
    v[j] = (f16)x;
  }
  *(f16x8*)&wf[(size_t)idx * 8] = v;
}

// Weight prep, 1x1: orig f32 [Cout][Cin] -> [ks][cf][lane][8] f16
__global__ __launch_bounds__(256) void k_wprep1(
    const float* __restrict__ w, f16* __restrict__ wf,
    int Cout, int Cin, int KS, int CoF)
{
  int idx = blockIdx.x * blockDim.x + threadIdx.x;
  int total = KS * CoF * 64;
  if (idx >= total) return;
  int lane = idx & 63;
  int cf = (idx >> 6) % CoF;
  int ks = (idx >> 6) / CoF;
  int co = cf * 16 + (lane & 15);
  f16x8 v = zero8();
#pragma unroll
  for (int j = 0; j < 8; ++j) {
    int cip = ks * 32 + (lane >> 4) * 8 + j;
    float x = 0.f;
    if (co < Cout && cip < Cin) x = w[(size_t)co * Cin + cip];
    v[j] = (f16)x;
  }
  *(f16x8*)&wf[(size_t)idx * 8] = v;
}

// ---------------------------------------------------------------------------
// Warp + concat + source, NHWC f16 out. fused: [b][pix][288] (259..287 = pads)
// ---------------------------------------------------------------------------
__global__ __launch_bounds__(256) void k_warp_fuse_h(
    const float* __restrict__ feat1, const float* __restrict__ feat2,
    const float* __restrict__ flowf, const float* __restrict__ flowb,
    const float* __restrict__ edge1, const float* __restrict__ edge2,
    f16* __restrict__ fused, f16* __restrict__ src)
{
  int idx = blockIdx.x * blockDim.x + threadIdx.x;
  if (idx >= Bn * 8 * HWl) return;
  int pix = idx % HWl;
  int cq = (idx / HWl) & 7;
  int b = idx / (HWl * 8);
  int j = pix % FW;
  int i = pix / FW;

  const int y4 = 4 * i + 1, x4 = 4 * j + 1;
  const float* p;
  p = flowf + (size_t)((b * 2 + 0) * Hh + y4) * Wh + x4;
  float fx1 = 0.03125f * (p[0] + p[1] + p[Wh] + p[Wh + 1]);
  p = flowf + (size_t)((b * 2 + 1) * Hh + y4) * Wh + x4;
  float fy1 = 0.03125f * (p[0] + p[1] + p[Wh] + p[Wh + 1]);
  p = flowb + (size_t)((b * 2 + 0) * Hh + y4) * Wh + x4;
  float fx2 = 0.03125f * (p[0] + p[1] + p[Wh] + p[Wh + 1]);
  p = flowb + (size_t)((b * 2 + 1) * Hh + y4) * Wh + x4;
  float fy2 = 0.03125f * (p[0] + p[1] + p[Wh] + p[Wh + 1]);

  float sx1 = fminf(fmaxf((float)j + fx1, 0.f), (float)(FW - 1));
  float sy1 = fminf(fmaxf((float)i + fy1, 0.f), (float)(FH - 1));
  float sx2 = fminf(fmaxf((float)j + fx2, 0.f), (float)(FW - 1));
  float sy2 = fminf(fmaxf((float)i + fy2, 0.f), (float)(FH - 1));

  int x10 = (int)floorf(sx1), y10 = (int)floorf(sy1);
  int x11 = min(x10 + 1, FW - 1), y11 = min(y10 + 1, FH - 1);
  float wx1 = sx1 - (float)x10, wy1 = sy1 - (float)y10;
  int x20 = (int)floorf(sx2), y20 = (int)floorf(sy2);
  int x21 = min(x20 + 1, FW - 1), y21 = min(y20 + 1, FH - 1);
  float wx2 = sx2 - (float)x20, wy2 = sy2 - (float)y20;

  float a00 = (1.f - wx1) * (1.f - wy1), a01 = wx1 * (1.f - wy1);
  float a10 = (1.f - wx1) * wy1,         a11 = wx1 * wy1;
  float c00 = (1.f - wx2) * (1.f - wy2), c01 = wx2 * (1.f - wy2);
  float c10 = (1.f - wx2) * wy2,         c11 = wx2 * wy2;
  int o00 = y10 * FW + x10, o01 = y10 * FW + x11, o10 = y11 * FW + x10, o11 = y11 * FW + x11;
  int q00 = y20 * FW + x20, q01 = y20 * FW + x21, q10 = y21 * FW + x20, q11 = y21 * FW + x21;

  f16* fp = fused + ((size_t)b * HWl + pix) * 288;
  f16* sp = src + ((size_t)b * HWl + pix) * 128;

  if (cq == 0) {
    p = edge1 + (size_t)(b * Hh + y4) * Wh + x4;
    float e1v = 0.25f * (p[0] + p[1] + p[Wh] + p[Wh + 1]);
    p = edge2 + (size_t)(b * Hh + y4) * Wh + x4;
    float e2v = 0.25f * (p[0] + p[1] + p[Wh] + p[Wh + 1]);
    fp[256] = (f16)e1v;
    fp[257] = (f16)e2v;
    fp[258] = (f16)0.5f;
#pragma unroll
    for (int c = 259; c < 288; ++c) fp[c] = (f16)0.f;
  }

  int c0 = cq * 16;
  for (int c = c0; c < c0 + 16; ++c) {
    const float* f1 = feat1 + (size_t)(b * Cn + c) * HWl;
    const float* f2 = feat2 + (size_t)(b * Cn + c) * HWl;
    float v1 = f1[o00] * a00 + f1[o01] * a01 + f1[o10] * a10 + f1[o11] * a11;
    float v2 = f2[q00] * c00 + f2[q01] * c01 + f2[q10] * c10 + f2[q11] * c11;
    fp[c] = (f16)v1;
    fp[128 + c] = (f16)v2;
    sp[c] = (f16)(0.5f * (v1 + v2));
  }
}

// ---------------------------------------------------------------------------
// MFMA 3x3 conv, NHWC f16. Block = 4 waves; wave w handles tile row w.
// Block tile: 4 rows x 32 cols x (NF*16) co. A staged in LDS per 32-ci slice
// (80 B/px stride -> ~conflict-free frag reads). B frags read from prepped
// global (L2-hot). UP=1: input bilinearly 4x-upsampled from (96,160) on the fly.
// ---------------------------------------------------------------------------
template<int ACT, int UP, int NF>
__global__ __launch_bounds__(256) void k_conv3m(
    const f16* __restrict__ Xin, const f16* __restrict__ Wf,
    const float* __restrict__ bias, f16* __restrict__ Out,
    int KS, int CoF, int Cs_in, int Cs_out, int Wd, int Ht,
    int in_r0, int in_rows, int out_r0, int out_rows, int ogr0, int ogr1)
{
  __shared__ f16 sA[8160];   // 6 rows x 34 cols x 40 f16 (80 B/px)
  int tid = threadIdx.x;
  int wv = tid >> 6, lane = tid & 63;
  int l15 = lane & 15, l4 = lane >> 4;
  int colTiles = Wd >> 5;
  int tileC = blockIdx.x % colTiles, tileR = blockIdx.x / colTiles;
  int b = blockIdx.z;
  int co0 = blockIdx.y * (NF * 16);
  int cfB = blockIdx.y * NF;
  int rowBaseOut = ogr0 + tileR * 4;
  int rowBase = rowBaseOut - 1;
  int colBase = tileC * 32;

  f32x4 acc[2][NF];
#pragma unroll
  for (int mf = 0; mf < 2; ++mf)
#pragma unroll
    for (int nf = 0; nf < NF; ++nf) acc[mf][nf] = zero4();

  for (int cs = 0; cs < KS; ++cs) {
    // ---- stage A halo tile (6 x 34 x 32ci), 16B units ----
    for (int u = tid; u < 816; u += 256) {
      int s = u & 3;
      int pxy = u >> 2;           // 0..203
      int x = pxy % 34;
      int y = pxy / 34;
      int gy = rowBase + y;
      int gx = colBase + x - 1;
      f16x8 v = zero8();
      if (UP) {
        if (gy >= 0 && gy < Ht && gx >= 0 && gx < Wd) {
          float uy = ((float)gy + 0.5f) * 0.25f - 0.5f;
          uy = fminf(fmaxf(uy, 0.f), (float)(FH - 1));
          int y0 = (int)floorf(uy);
          int y1 = min(y0 + 1, FH - 1);
          float fy = uy - (float)y0;
          float ux = ((float)gx + 0.5f) * 0.25f - 0.5f;
          ux = fminf(fmaxf(ux, 0.f), (float)(FW - 1));
          int x0 = (int)floorf(ux);
          int x1 = min(x0 + 1, FW - 1);
          float fx = ux - (float)x0;
          const f16* xb = Xin + (size_t)b * HWl * 128 + cs * 32 + s * 8;
          f16x8 v00 = *(const f16x8*)&xb[(size_t)(y0 * FW + x0) * 128];
          f16x8 v01 = *(const f16x8*)&xb[(size_t)(y0 * FW + x1) * 128];
          f16x8 v10 = *(const f16x8*)&xb[(size_t)(y1 * FW + x0) * 128];
          f16x8 v11 = *(const f16x8*)&xb[(size_t)(y1 * FW + x1) * 128];
#pragma unroll
          for (int jj = 0; jj < 8; ++jj) {
            float t0 = (float)v00[jj] * (1.f - fx) + (float)v01[jj] * fx;
            float t1 = (float)v10[jj] * (1.f - fx) + (float)v11[jj] * fx;
            v[jj] = (f16)(t0 * (1.f - fy) + t1 * fy);
          }
        }
      } else {
        if (gy >= in_r0 && gy < in_r0 + in_rows && gx >= 0 && gx < Wd)
          v = *(const f16x8*)&Xin[(((size_t)b * in_rows + (gy - in_r0)) * Wd + gx) * Cs_in
                                  + cs * 32 + s * 8];
      }
      *(f16x8*)((char*)sA + pxy * 80 + s * 16) = v;
    }
    __syncthreads();
    // ---- compute ----
#pragma unroll
    for (int ky = 0; ky < 3; ++ky) {
#pragma unroll
      for (int kx = 0; kx < 3; ++kx) {
        const char* ab = (const char*)sA;
        f16x8 a0 = *(const f16x8*)(ab + ((wv + ky) * 34 + l15 + kx) * 80 + l4 * 16);
        f16x8 a1 = *(const f16x8*)(ab + ((wv + ky) * 34 + l15 + 16 + kx) * 80 + l4 * 16);
        int tap = ky * 3 + kx;
#pragma unroll
        for (int nf = 0; nf < NF; ++nf) {
          f16x8 bf = *(const f16x8*)&Wf[((((size_t)tap * KS + cs) * CoF + cfB + nf) * 64 + lane) * 8];
          acc[0][nf] = __builtin_amdgcn_mfma_f32_16x16x32_f16(a0, bf, acc[0][nf], 0, 0, 0);
          acc[1][nf] = __builtin_amdgcn_mfma_f32_16x16x32_f16(a1, bf, acc[1][nf], 0, 0, 0);
        }
      }
    }
    __syncthreads();
  }

  int r = rowBaseOut + wv;
  if (r < ogr1) {
    size_t rowoff = ((size_t)b * out_rows + (r - out_r0)) * Wd;
#pragma unroll
    for (int nf = 0; nf < NF; ++nf) {
      int co = co0 + nf * 16 + l15;
      float bv = bias[co];
#pragma unroll
      for (int mf = 0; mf < 2; ++mf) {
        int xo = colBase + mf * 16 + l4 * 4;
#pragma unroll
        for (int rg = 0; rg < 4; ++rg) {
          float v = activ<ACT>(acc[mf][nf][rg] + bv);
          Out[(rowoff + xo + rg) * Cs_out + co] = (f16)v;
        }
      }
    }
  }
}

// ---------------------------------------------------------------------------
// MFMA 1x1 conv (pure GEMM, no LDS). Wave = 32px x up-to-64co tile.
// A frags straight from global NHWC (L2-hot), B from prepped weights.
// ---------------------------------------------------------------------------
template<int ACT, int RES>
__global__ __launch_bounds__(256) void k_gemm1x1(
    const f16* __restrict__ X, const f16* __restrict__ Wf,
    const float* __restrict__ bias, f16* __restrict__ Out,
    int KS, int CoF, int Cs_in, int Cs_out, int Cr, int coTiles, int pixTiles)
{
  int wid = blockIdx.x * 4 + (threadIdx.x >> 6);
  int lane = threadIdx.x & 63;
  int total = pixTiles * coTiles;
  if (wid >= total) return;
  int coT = wid % coTiles;
  int pixT = wid / coTiles;
  int nfc = min(4, CoF - coT * 4);
  int l15 = lane & 15, l4 = lane >> 4;

  f32x4 acc[2][4];
#pragma unroll
  for (int mf = 0; mf < 2; ++mf)
#pragma unroll
    for (int nf = 0; nf < 4; ++nf) acc[mf][nf] = zero4();

  int pA0 = pixT * 32 + l15;
  for (int ks = 0; ks < KS; ++ks) {
    f16x8 a0 = *(const f16x8*)&X[(size_t)pA0 * Cs_in + ks * 32 + l4 * 8];
    f16x8 a1 = *(const f16x8*)&X[(size_t)(pA0 + 16) * Cs_in + ks * 32 + l4 * 8];
#pragma unroll
    for (int nf = 0; nf < 4; ++nf) {
      if (nf < nfc) {
        f16x8 bf = *(const f16x8*)&Wf[(((size_t)ks * CoF + coT * 4 + nf) * 64 + lane) * 8];
        acc[0][nf] = __builtin_amdgcn_mfma_f32_16x16x32_f16(a0, bf, acc[0][nf], 0, 0, 0);
        acc[1][nf] = __builtin_amdgcn_mfma_f32_16x16x32_f16(a1, bf, acc[1][nf], 0, 0, 0);
      }
    }
  }
#pragma unroll
  for (int nf = 0; nf < 4; ++nf) {
    if (nf < nfc) {
      int co = coT * 64 + nf * 16 + l15;
      if (co < Cr) {
        float bv = bias[co];
#pragma unroll
        for (int mf = 0; mf < 2; ++mf) {
          int p0 = pixT * 32 + mf * 16 + l4 * 4;
#pragma unroll
          for (int rg = 0; rg < 4; ++rg) {
            float v = activ<ACT>(acc[mf][nf][rg] + bv);
            size_t o = (size_t)(p0 + rg) * Cs_out + co;
            if (RES) v += (float)Out[o];
            Out[o] = (f16)v;
          }
        }
      }
    }
  }
}

// ---------------------------------------------------------------------------
// GroupNorm on NHWC f16, two stage.
// ---------------------------------------------------------------------------
__global__ __launch_bounds__(256) void k_gn_part_h(
    const f16* __restrict__ X, float* __restrict__ part)
{
  int s = blockIdx.x & 7;
  int g = (blockIdx.x >> 3) & 7;
  int b = blockIdx.x >> 6;
  int tid = threadIdx.x;
  const f16* Xp = X + (size_t)b * HWl * 128 + g * 16 + (tid & 1) * 8;
  float sum = 0.f, ss = 0.f;
  for (int p = s * 1920 + (tid >> 1); p < (s + 1) * 1920; p += 128) {
    f16x8 v = *(const f16x8*)&Xp[(size_t)p * 128];
#pragma unroll
    for (int jj = 0; jj < 8; ++jj) { float f = (float)v[jj]; sum += f; ss += f * f; }
  }
  __shared__ float sh1[256], sh2[256];
  sh1[tid] = sum; sh2[tid] = ss;
  __syncthreads();
  for (int st = 128; st > 0; st >>= 1) {
    if (tid < st) { sh1[tid] += sh1[tid + st]; sh2[tid] += sh2[tid + st]; }
    __syncthreads();
  }
  if (tid == 0) {
    part[((b * 8 + g) * 8 + s) * 2] = sh1[0];
    part[((b * 8 + g) * 8 + s) * 2 + 1] = sh2[0];
  }
}

__global__ __launch_bounds__(256) void k_gn_apply_h(
    const f16* __restrict__ X, const float* __restrict__ gw,
    const float* __restrict__ gb, const float* __restrict__ part,
    f16* __restrict__ Q)
{
  int idx = blockIdx.x * blockDim.x + threadIdx.x;
  int total = Bn * HWl * 16;
  if (idx >= total) return;
  int u = idx & 15;
  int pix = (idx >> 4) % HWl;
  int b = idx / (16 * HWl);
  int c0 = u * 8;
  int g = c0 >> 4;
  const float* pp = part + ((b * 8 + g) * 8) * 2;
  float sum = 0.f, ss = 0.f;
#pragma unroll
  for (int s = 0; s < 8; ++s) { sum += pp[s * 2]; ss += pp[s * 2 + 1]; }
  const float n = 16.f * HWl;
  float mean = sum / n;
  float var = ss / n - mean * mean;
  float inv = rsqrtf(var + 1e-5f);
  f16x8 v = *(const f16x8*)&X[((size_t)b * HWl + pix) * 128 + c0];
  f16x8 r;
#pragma unroll
  for (int jj = 0; jj < 8; ++jj) {
    int c = c0 + jj;
    r[jj] = (f16)(((float)v[jj] - mean) * (gw[c] * inv) + gb[c]);
  }
  *(f16x8*)&Q[((size_t)b * HWl + pix) * 128 + c0] = r;
}

// softmax over the 9 points; attn NHWC [b][pix][48], heads at c = head*9
__global__ __launch_bounds__(256) void k_softmax9_h(f16* __restrict__ a)
{
  int idx = blockIdx.x * blockDim.x + threadIdx.x;
  if (idx >= Bn * NHd * HWl) return;
  int pix = idx % HWl;
  int head = (idx / HWl) & 3;
  int b = idx / (HWl * NHd);
  f16* base = a + ((size_t)b * HWl + pix) * 48 + head * 9;
  float v[9];
  float m = -1e30f;
#pragma unroll
  for (int p0 = 0; p0 < 9; ++p0) { v[p0] = (float)base[p0]; m = fmaxf(m, v[p0]); }
  float s = 0.f;
#pragma unroll
  for (int p0 = 0; p0 < 9; ++p0) { v[p0] = expf(v[p0] - m); s += v[p0]; }
  float inv = 1.f / s;
#pragma unroll
  for (int p0 = 0; p0 < 9; ++p0) base[p0] = (f16)(v[p0] * inv);
}

// ---------------------------------------------------------------------------
// Deformable sampling, all NHWC. Thread per (b, head, pix), 32 head-channels.
// ---------------------------------------------------------------------------
__global__ __launch_bounds__(256) void k_deform_h(
    const f16* __restrict__ vals, const f16* __restrict__ off,
    const f16* __restrict__ attn, f16* __restrict__ outa)
{
  int idx = blockIdx.x * blockDim.x + threadIdx.x;
  if (idx >= Bn * NHd * HWl) return;
  int pix = idx % HWl;
  int head = (idx / HWl) & 3;
  int b = idx / (HWl * NHd);
  int j = pix % FW, i = pix / FW;

  const float kx = (float)FW / (float)(FW - 1);
  const float ky = (float)FH / (float)(FH - 1);
  const f16* vb = vals + (size_t)b * HWl * 128 + head * 32;
  const f16* ab = attn + ((size_t)b * HWl + pix) * 48 + head * 9;
  const f16* ob = off + ((size_t)b * HWl + pix) * 80 + head * 18;

  float acc[32];
#pragma unroll
  for (int k = 0; k < 32; ++k) acc[k] = 0.f;

#pragma unroll
  for (int p0 = 0; p0 < 9; ++p0) {
    float ox = (float)ob[p0 * 2];
    float oy = (float)ob[p0 * 2 + 1];
    float aw = (float)ab[p0];
    float xf = ((float)j + ox) * kx - 0.5f;
    float yf = ((float)i + oy) * ky - 0.5f;
    xf = fminf(fmaxf(xf, 0.f), (float)(FW - 1));
    yf = fminf(fmaxf(yf, 0.f), (float)(FH - 1));
    int x0 = (int)floorf(xf), y0 = (int)floorf(yf);
    int x1 = min(x0 + 1, FW - 1), y1 = min(y0 + 1, FH - 1);
    float fx = xf - (float)x0, fy = yf - (float)y0;
    float w00 = aw * (1.f - fx) * (1.f - fy);
    float w01 = aw * fx * (1.f - fy);
    float w10 = aw * (1.f - fx) * fy;
    float w11 = aw * fx * fy;
    const f16x8* c00 = (const f16x8*)&vb[(size_t)(y0 * FW + x0) * 128];
    const f16x8* c01 = (const f16x8*)&vb[(size_t)(y0 * FW + x1) * 128];
    const f16x8* c10 = (const f16x8*)&vb[(size_t)(y1 * FW + x0) * 128];
    const f16x8* c11 = (const f16x8*)&vb[(size_t)(y1 * FW + x1) * 128];
#pragma unroll
    for (int k8 = 0; k8 < 4; ++k8) {
      f16x8 a = c00[k8], bb = c01[k8], cc = c10[k8], dd = c11[k8];
#pragma unroll
      for (int jj = 0; jj < 8; ++jj)
        acc[k8 * 8 + jj] += w00 * (float)a[jj] + w01 * (float)bb[jj]
                          + w10 * (float)cc[jj] + w11 * (float)dd[jj];
    }
  }
  f16* op = outa + ((size_t)b * HWl + pix) * 128 + head * 32;
#pragma unroll
  for (int k = 0; k < 32; ++k) op[k] = (f16)acc[k];
}

// ---------------------------------------------------------------------------
// dec2: 32->3 direct conv from NHWC f16 window rows [b0,b0+brows) + sigmoid,
// writes NCHW f32 output rows [c0, c0+96).
// ---------------------------------------------------------------------------
__global__ __launch_bounds__(256) void k_dec2_h(
    const f16* __restrict__ Xb, const float* __restrict__ w,
    const float* __restrict__ bias, float* __restrict__ out,
    int c0, int b0, int brows)
{
  int idx = blockIdx.x * blockDim.x + threadIdx.x;
  if (idx >= Bn * 96 * Wh) return;
  int x = idx % Wh;
  int y = c0 + (idx / Wh) % 96;
  int b = idx / (Wh * 96);
  float a0 = bias[0], a1 = bias[1], a2 = bias[2];
#pragma unroll
  for (int ky = 0; ky < 3; ++ky) {
    int gy = y + ky - 1;
    if (gy < 0 || gy >= Hh) continue;
#pragma unroll
    for (int kxx = 0; kxx < 3; ++kxx) {
      int gx = x + kxx - 1;
      if (gx < 0 || gx >= Wh) continue;
      int tap = ky * 3 + kxx;
      const f16* px = Xb + ((size_t)(b * brows + (gy - b0)) * Wh + gx) * 32;
#pragma unroll
      for (int k8 = 0; k8 < 4; ++k8) {
        f16x8 v = *(const f16x8*)&px[k8 * 8];
#pragma unroll
        for (int jj = 0; jj < 8; ++jj) {
          int ci = k8 * 8 + jj;
          float f = (float)v[jj];
          a0 += f * w[(0 * 32 + ci) * 9 + tap];
          a1 += f * w[(1 * 32 + ci) * 9 + tap];
          a2 += f * w[(2 * 32 + ci) * 9 + tap];
        }
      }
    }
  }
  size_t o = ((size_t)(b * 3 + 0) * Hh + y) * Wh + x;
  out[o] = 1.f / (1.f + expf(-a0));
  out[o + (size_t)Hh * Wh] = 1.f / (1.f + expf(-a1));
  out[o + (size_t)2 * Hh * Wh] = 1.f / (1.f + expf(-a2));
}

// ---------------------------------------------------------------------------
extern "C" void kernel_launch(void* const* d_in, const int* in_sizes, int n_in,
                              void* d_out, int out_size, void* d_ws, size_t ws_size,
                              hipStream_t stream) {
  (void)in_sizes; (void)n_in; (void)out_size; (void)ws_size;
  const float* feat1  = (const float*)d_in[0];
  const float* feat2  = (const float*)d_in[1];
  const float* flowf  = (const float*)d_in[2];
  const float* flowb  = (const float*)d_in[3];
  const float* edge1  = (const float*)d_in[4];
  const float* edge2  = (const float*)d_in[5];
  const float* fuse_w0 = (const float*)d_in[6];
  const float* fuse_b0 = (const float*)d_in[7];
  const float* fuse_w1 = (const float*)d_in[8];
  const float* fuse_b1 = (const float*)d_in[9];
  const float* gn_g   = (const float*)d_in[10];
  const float* gn_b   = (const float*)d_in[11];
  const float* off_w0 = (const float*)d_in[12];
  const float* off_b0 = (const float*)d_in[13];
  const float* off_w1 = (const float*)d_in[14];
  const float* off_b1 = (const float*)d_in[15];
  const float* aw_w0  = (const float*)d_in[16];
  const float* aw_b0  = (const float*)d_in[17];
  const float* aw_w1  = (const float*)d_in[18];
  const float* aw_b1  = (const float*)d_in[19];
  const float* val_w  = (const float*)d_in[20];
  const float* val_b  = (const float*)d_in[21];
  const float* out_w  = (const float*)d_in[22];
  const float* out_b  = (const float*)d_in[23];
  const float* ffn_w0 = (const float*)d_in[24];
  const float* ffn_b0 = (const float*)d_in[25];
  const float* ffn_w1 = (const float*)d_in[26];
  const float* ffn_b1 = (const float*)d_in[27];
  const float* dec_w0 = (const float*)d_in[28];
  const float* dec_b0 = (const float*)d_in[29];
  const float* dec_w1 = (const float*)d_in[30];
  const float* dec_b1 = (const float*)d_in[31];
  const float* dec_w2 = (const float*)d_in[32];
  const float* dec_b2 = (const float*)d_in[33];
  float* out = (float*)d_out;

  // ---- workspace layout (f16 units), ~60 MB total ----
  f16* ws16 = (f16*)d_ws;
  size_t o = 0;
  auto alloc = [&](size_t n) { f16* p = ws16 + o; o += (n + 7) & ~(size_t)7; return p; };
  f16* xbuf  = alloc((size_t)2 * HWl * 128);
  f16* regA  = alloc((size_t)2 * HWl * 288);   // fused / t_off / t_aw / ffn_t / bufA
  f16* regB  = alloc((size_t)2 * HWl * 128);   // source / out_attn
  f16* regC  = alloc((size_t)2 * HWl * 128);   // fuse0-out / qb
  f16* offb  = alloc((size_t)2 * HWl * 80);
  f16* attnb = alloc((size_t)2 * HWl * 48);
  f16* regF  = alloc((size_t)2 * 98 * 640 * 32); // valsb / bufB
  f16* wfF0 = alloc(9 * 288 * 128);
  f16* wfF1 = alloc(9 * 128 * 128);
  f16* wfO0 = alloc(9 * 128 * 128);
  f16* wfA0 = alloc(9 * 128 * 128);
  f16* wfD0 = alloc(9 * 128 * 64);
  f16* wfD1 = alloc(9 * 64 * 32);
  f16* w1O  = alloc(4 * 5 * 512);
  f16* w1A  = alloc(4 * 3 * 512);
  f16* w1V  = alloc(4 * 8 * 512);
  f16* w1U  = alloc(4 * 8 * 512);
  f16* w1G0 = alloc(4 * 16 * 512);
  f16* w1G1 = alloc(8 * 8 * 512);
  float* gnp = (float*)alloc(512);             // 256 f32 partials

  f16* fused = regA;
  f16* t_off = regA;
  f16* t_aw  = regA;
  f16* ffn_t = regA;
  f16* bufA  = regA;
  f16* src_h = regB;
  f16* out_attn = regB;
  f16* tmp_h = regC;
  f16* qb    = regC;
  f16* valsb = regF;
  f16* bufB  = regF;

  dim3 blk(256);
  auto pg = [](long n) { return dim3((unsigned)((n + 255) / 256)); };

  // ---- weight prep ----
  k_wprep3<<<pg(9L * 9 * 8 * 64), blk, 0, stream>>>(fuse_w0, wfF0, 128, 259, 128, 9, 8);
  k_wprep3<<<pg(9L * 4 * 8 * 64), blk, 0, stream>>>(fuse_w1, wfF1, 128, 128, 128, 4, 8);
  k_wprep3<<<pg(9L * 4 * 8 * 64), blk, 0, stream>>>(off_w0, wfO0, 128, 32, 32, 4, 8);
  k_wprep3<<<pg(9L * 4 * 8 * 64), blk, 0, stream>>>(aw_w0, wfA0, 128, 32, 32, 4, 8);
  k_wprep3<<<pg(9L * 4 * 4 * 64), blk, 0, stream>>>(dec_w0, wfD0, 64, 128, 64, 4, 4);
  k_wprep3<<<pg(9L * 2 * 2 * 64), blk, 0, stream>>>(dec_w1, wfD1, 32, 64, 32, 2, 2);
  k_wprep1<<<pg(4L * 5 * 64), blk, 0, stream>>>(off_w1, w1O, 72, 128, 4, 5);
  k_wprep1<<<pg(4L * 3 * 64), blk, 0, stream>>>(aw_w1, w1A, 36, 128, 4, 3);
  k_wprep1<<<pg(4L * 8 * 64), blk, 0, stream>>>(val_w, w1V, 128, 128, 4, 8);
  k_wprep1<<<pg(4L * 8 * 64), blk, 0, stream>>>(out_w, w1U, 128, 128, 4, 8);
  k_wprep1<<<pg(4L * 16 * 64), blk, 0, stream>>>(ffn_w0, w1G0, 256, 128, 4, 16);
  k_wprep1<<<pg(8L * 8 * 64), blk, 0, stream>>>(ffn_w1, w1G1, 128, 256, 8, 8);

  // ---- 1. warp + concat + source ----
  k_warp_fuse_h<<<pg(2L * 8 * HWl), blk, 0, stream>>>(feat1, feat2, flowf, flowb,
                                                      edge1, edge2, fused, src_h);
  // ---- 2-3. fuse convs ----
  dim3 gF(24 * 5, 2, 2);
  k_conv3m<1, 0, 4><<<gF, blk, 0, stream>>>(fused, wfF0, fuse_b0, tmp_h,
      9, 8, 288, 128, FW, FH, 0, FH, 0, FH, 0, FH);
  k_conv3m<1, 0, 4><<<gF, blk, 0, stream>>>(tmp_h, wfF1, fuse_b1, xbuf,
      4, 8, 128, 128, FW, FH, 0, FH, 0, FH, 0, FH);
  // ---- 4. group norm ----
  k_gn_part_h<<<dim3(128), blk, 0, stream>>>(xbuf, gnp);
  k_gn_apply_h<<<pg(2L * HWl * 16), blk, 0, stream>>>(xbuf, gn_g, gn_b, gnp, qb);
  // ---- 5-6. offsets ----
  k_conv3m<1, 0, 4><<<gF, blk, 0, stream>>>(qb, wfO0, off_b0, t_off,
      4, 8, 128, 128, FW, FH, 0, FH, 0, FH, 0, FH);
  k_gemm1x1<0, 0><<<dim3(480), blk, 0, stream>>>(t_off, w1O, off_b1, offb,
      4, 5, 128, 80, 72, 2, 960);
  // ---- 7-8. attention weights + softmax ----
  k_conv3m<1, 0, 4><<<gF, blk, 0, stream>>>(qb, wfA0, aw_b0, t_aw,
      4, 8, 128, 128, FW, FH, 0, FH, 0, FH, 0, FH);
  k_gemm1x1<0, 0><<<dim3(240), blk, 0, stream>>>(t_aw, w1A, aw_b1, attnb,
      4, 3, 128, 48, 36, 1, 960);
  k_softmax9_h<<<pg(2L * NHd * HWl), blk, 0, stream>>>(attnb);
  // ---- 9. vals ----
  k_gemm1x1<0, 0><<<dim3(480), blk, 0, stream>>>(src_h, w1V, val_b, valsb,
      4, 8, 128, 128, 128, 2, 960);
  // ---- 10. deform ----
  k_deform_h<<<pg(2L * NHd * HWl), blk, 0, stream>>>(valsb, offb, attnb, out_attn);
  // ---- 11. out-proj (residual into xbuf) ----
  k_gemm1x1<0, 1><<<dim3(480), blk, 0, stream>>>(out_attn, w1U, out_b, xbuf,
      4, 8, 128, 128, 128, 2, 960);
  // ---- 12-13. FFN ----
  k_gemm1x1<2, 0><<<dim3(960), blk, 0, stream>>>(xbuf, w1G0, ffn_b0, ffn_t,
      4, 16, 128, 256, 256, 4, 960);
  k_gemm1x1<0, 1><<<dim3(480), blk, 0, stream>>>(ffn_t, w1G1, ffn_b1, xbuf,
      8, 8, 256, 128, 128, 2, 960);

  // ---- 14. decoder, 4 chunks of 96 rows; upsample fused into dec0 staging ----
  for (int c0 = 0; c0 < Hh; c0 += 96) {
    int c1 = c0 + 96;
    int a0 = c0 - 2 > 0 ? c0 - 2 : 0;
    int a1 = c1 + 2 < Hh ? c1 + 2 : Hh;
    int b0 = c0 - 1 > 0 ? c0 - 1 : 0;
    int b1 = c1 + 1 < Hh ? c1 + 1 : Hh;
    int ar = a1 - a0, br = b1 - b0;
    dim3 gD0((unsigned)(((ar + 3) / 4) * 20), 1, 2);
    k_conv3m<1, 1, 4><<<gD0, blk, 0, stream>>>(xbuf, wfD0, dec_b0, bufA,
        4, 4, 128, 64, Wh, Hh, 0, 0, a0, ar, a0, a1);
    dim3 gD1((unsigned)(((br + 3) / 4) * 20), 1, 2);
    k_conv3m<1, 0, 2><<<gD1, blk, 0, stream>>>(bufA, wfD1, dec_b1, bufB,
        2, 2, 64, 32, Wh, Hh, a0, ar, b0, br, b0, b1);
    k_dec2_h<<<pg(2L * 96 * Wh), blk, 0, stream>>>(bufB, dec_w2, dec_b2, out, c0, b0, br);
  }
}

// Round 5
// 610.508 us; speedup vs baseline: 16.8882x; 1.0238x over previous
//
#include <hip/hip_runtime.h>

typedef _Float16 f16;
typedef _Float16 f16x8 __attribute__((ext_vector_type(8)));
typedef float f32x4 __attribute__((ext_vector_type(4)));

constexpr int Bn = 2, Cn = 128, FH = 96, FW = 160, Hh = 384, Wh = 640;
constexpr int HWl = FH * FW;   // 15360
constexpr int NHd = 4, NPt = 9;

#define DEVINL __device__ __forceinline__

DEVINL f32x4 zero4() { f32x4 z; z[0] = 0.f; z[1] = 0.f; z[2] = 0.f; z[3] = 0.f; return z; }
DEVINL f16x8 zero8() {
  f16x8 z;
#pragma unroll
  for (int j = 0; j < 8; ++j) z[j] = (f16)0.f;
  return z;
}

template<int ACT> DEVINL float activ(float v) {
  if (ACT == 1) return v >= 0.f ? v : 0.1f * v;                           // leaky relu
  if (ACT == 2) return 0.5f * v * (1.f + erff(v * 0.70710678118654752f)); // exact gelu
  if (ACT == 3) return 1.f / (1.f + expf(-v));                            // sigmoid
  return v;
}

// ---------------------------------------------------------------------------
// Merged weight prep (12 jobs in one launch). 3x3 jobs (taps=9) produce
// [tap][ks][cf][lane][8]; 1x1 jobs (taps=1) produce [ks][cf][lane][8].
// k-convention: k = (lane>>4)*8 + j, matching the A-fragment convention.
// Grouped convs zero-padded to full Cin (band = (co/cout_g)*cin_g).
// For 1x1: cin_g=Cin, cout_g=Cout (band=0).
// ---------------------------------------------------------------------------
struct PrepJob { const float* w; f16* wf; int Cout, cin_g, cout_g, KS, CoF, taps, blk0; };
struct PrepArgs { PrepJob j[12]; };

__global__ __launch_bounds__(256) void k_wprep_all(PrepArgs a)
{
  int jb = 0;
#pragma unroll
  for (int t = 1; t < 12; ++t) if ((int)blockIdx.x >= a.j[t].blk0) jb = t;
  PrepJob J = a.j[jb];
  int idx = (blockIdx.x - J.blk0) * 256 + threadIdx.x;
  int total = J.taps * J.KS * J.CoF * 64;
  if (idx >= total) return;
  int lane = idx & 63;
  int rest = idx >> 6;
  int cf = rest % J.CoF;
  int rest2 = rest / J.CoF;
  int ks = rest2 % J.KS;
  int tap = rest2 / J.KS;
  int co = cf * 16 + (lane & 15);
  f16x8 v = zero8();
#pragma unroll
  for (int j = 0; j < 8; ++j) {
    int cip = ks * 32 + (lane >> 4) * 8 + j;
    int cil = cip - (co / J.cout_g) * J.cin_g;
    float x = 0.f;
    if (co < J.Cout && cil >= 0 && cil < J.cin_g)
      x = J.w[((size_t)co * J.cin_g + cil) * J.taps + tap];
    v[j] = (f16)x;
  }
  *(f16x8*)&J.wf[(size_t)idx * 8] = v;
}

// ---------------------------------------------------------------------------
// NCHW f32 -> NHWC f16 transpose for feat1+feat2 in one launch.
// Lane layout: cq (8 x 16ch) fastest -> writes fully contiguous.
// ---------------------------------------------------------------------------
__global__ __launch_bounds__(256) void k_tr_h(
    const float* __restrict__ feat1, const float* __restrict__ feat2,
    f16* __restrict__ t1, f16* __restrict__ t2)
{
  int idx = blockIdx.x * blockDim.x + threadIdx.x;
  if (idx >= 2 * Bn * HWl * 8) return;
  int cq = idx & 7;
  int pix = (idx >> 3) % HWl;
  int z = idx / (8 * HWl);
  int b = z & 1;
  const float* src = (z >> 1) ? feat2 : feat1;
  f16* dst = (z >> 1) ? t2 : t1;
  int c0 = cq * 16;
  f16x8 v0, v1;
#pragma unroll
  for (int j = 0; j < 8; ++j) {
    v0[j] = (f16)src[(size_t)(b * Cn + c0 + j) * HWl + pix];
    v1[j] = (f16)src[(size_t)(b * Cn + c0 + 8 + j) * HWl + pix];
  }
  f16* dp = dst + ((size_t)b * HWl + pix) * 128 + c0;
  *(f16x8*)dp = v0;
  *(f16x8*)(dp + 8) = v1;
}

// ---------------------------------------------------------------------------
// Warp + concat + source, NHWC f16. Lane layout: cq fastest (8 thr/pixel) ->
// coalesced vector gathers (shared corner addresses) + contiguous stores.
// ---------------------------------------------------------------------------
__global__ __launch_bounds__(256) void k_warp_fuse_h(
    const f16* __restrict__ t1, const f16* __restrict__ t2,
    const float* __restrict__ flowf, const float* __restrict__ flowb,
    const float* __restrict__ edge1, const float* __restrict__ edge2,
    f16* __restrict__ fused, f16* __restrict__ src)
{
  int idx = blockIdx.x * blockDim.x + threadIdx.x;
  if (idx >= Bn * HWl * 8) return;
  int cq = idx & 7;
  int pix = (idx >> 3) % HWl;
  int b = idx / (8 * HWl);
  int j = pix % FW;
  int i = pix / FW;

  const int y4 = 4 * i + 1, x4 = 4 * j + 1;
  const float* p;
  p = flowf + (size_t)((b * 2 + 0) * Hh + y4) * Wh + x4;
  float fx1 = 0.03125f * (p[0] + p[1] + p[Wh] + p[Wh + 1]);
  p = flowf + (size_t)((b * 2 + 1) * Hh + y4) * Wh + x4;
  float fy1 = 0.03125f * (p[0] + p[1] + p[Wh] + p[Wh + 1]);
  p = flowb + (size_t)((b * 2 + 0) * Hh + y4) * Wh + x4;
  float fx2 = 0.03125f * (p[0] + p[1] + p[Wh] + p[Wh + 1]);
  p = flowb + (size_t)((b * 2 + 1) * Hh + y4) * Wh + x4;
  float fy2 = 0.03125f * (p[0] + p[1] + p[Wh] + p[Wh + 1]);

  float sx1 = fminf(fmaxf((float)j + fx1, 0.f), (float)(FW - 1));
  float sy1 = fminf(fmaxf((float)i + fy1, 0.f), (float)(FH - 1));
  float sx2 = fminf(fmaxf((float)j + fx2, 0.f), (float)(FW - 1));
  float sy2 = fminf(fmaxf((float)i + fy2, 0.f), (float)(FH - 1));

  int x10 = (int)floorf(sx1), y10 = (int)floorf(sy1);
  int x11 = min(x10 + 1, FW - 1), y11 = min(y10 + 1, FH - 1);
  float wx1 = sx1 - (float)x10, wy1 = sy1 - (float)y10;
  int x20 = (int)floorf(sx2), y20 = (int)floorf(sy2);
  int x21 = min(x20 + 1, FW - 1), y21 = min(y20 + 1, FH - 1);
  float wx2 = sx2 - (float)x20, wy2 = sy2 - (float)y20;

  float a00 = (1.f - wx1) * (1.f - wy1), a01 = wx1 * (1.f - wy1);
  float a10 = (1.f - wx1) * wy1,         a11 = wx1 * wy1;
  float c00 = (1.f - wx2) * (1.f - wy2), c01 = wx2 * (1.f - wy2);
  float c10 = (1.f - wx2) * wy2,         c11 = wx2 * wy2;

  int c0 = cq * 16;
  const f16* b1 = t1 + (size_t)b * HWl * 128 + c0;
  const f16* b2 = t2 + (size_t)b * HWl * 128 + c0;
  const f16x8* p100 = (const f16x8*)&b1[(size_t)(y10 * FW + x10) * 128];
  const f16x8* p101 = (const f16x8*)&b1[(size_t)(y10 * FW + x11) * 128];
  const f16x8* p110 = (const f16x8*)&b1[(size_t)(y11 * FW + x10) * 128];
  const f16x8* p111 = (const f16x8*)&b1[(size_t)(y11 * FW + x11) * 128];
  const f16x8* p200 = (const f16x8*)&b2[(size_t)(y20 * FW + x20) * 128];
  const f16x8* p201 = (const f16x8*)&b2[(size_t)(y20 * FW + x21) * 128];
  const f16x8* p210 = (const f16x8*)&b2[(size_t)(y21 * FW + x20) * 128];
  const f16x8* p211 = (const f16x8*)&b2[(size_t)(y21 * FW + x21) * 128];

  f16* fp = fused + ((size_t)b * HWl + pix) * 288;
  f16* sp = src + ((size_t)b * HWl + pix) * 128;

#pragma unroll
  for (int h = 0; h < 2; ++h) {
    f16x8 u00 = p100[h], u01 = p101[h], u10 = p110[h], u11 = p111[h];
    f16x8 w00 = p200[h], w01 = p201[h], w10 = p210[h], w11 = p211[h];
    f16x8 r1, r2, rs;
#pragma unroll
    for (int k = 0; k < 8; ++k) {
      float v1 = (float)u00[k] * a00 + (float)u01[k] * a01
               + (float)u10[k] * a10 + (float)u11[k] * a11;
      float v2 = (float)w00[k] * c00 + (float)w01[k] * c01
               + (float)w10[k] * c10 + (float)w11[k] * c11;
      r1[k] = (f16)v1; r2[k] = (f16)v2; rs[k] = (f16)(0.5f * (v1 + v2));
    }
    *(f16x8*)(fp + c0 + h * 8) = r1;
    *(f16x8*)(fp + 128 + c0 + h * 8) = r2;
    *(f16x8*)(sp + c0 + h * 8) = rs;
  }

  if (cq == 0) {
    p = edge1 + (size_t)(b * Hh + y4) * Wh + x4;
    float e1v = 0.25f * (p[0] + p[1] + p[Wh] + p[Wh + 1]);
    p = edge2 + (size_t)(b * Hh + y4) * Wh + x4;
    float e2v = 0.25f * (p[0] + p[1] + p[Wh] + p[Wh + 1]);
    fp[256] = (f16)e1v;
    fp[257] = (f16)e2v;
    fp[258] = (f16)0.5f;
#pragma unroll
    for (int c = 259; c < 288; ++c) fp[c] = (f16)0.f;
  }
}

// ---------------------------------------------------------------------------
// MFMA 3x3 conv, NHWC f16, register-prefetch double buffer.
// Block = 4 waves; wave w = tile row w. Block tile: 4 rows x 32 cols x NF*16 co.
// Per 32-ci slice: prefetch global (or 4 upsample corners) into regs during
// previous slice's MFMA phase; write->LDS (80 B/px stride); MFMA from LDS,
// B frags from prepped global (L2-hot).
// ---------------------------------------------------------------------------
template<int ACT, int UP, int NF>
__global__ __launch_bounds__(256) void k_conv3m(
    const f16* __restrict__ Xin, const f16* __restrict__ Wf,
    const float* __restrict__ bias, f16* __restrict__ Out,
    int KS, int CoF, int Cs_in, int Cs_out, int Wd, int Ht,
    int in_r0, int in_rows, int out_r0, int out_rows, int ogr0, int ogr1)
{
  __shared__ f16 sA[8160];   // 6 rows x 34 cols x 40 f16 (80 B/px)
  int tid = threadIdx.x;
  int wv = tid >> 6, lane = tid & 63;
  int l15 = lane & 15, l4 = lane >> 4;
  int colTiles = Wd >> 5;
  int tileC = blockIdx.x % colTiles, tileR = blockIdx.x / colTiles;
  int b = blockIdx.z;
  int co0 = blockIdx.y * (NF * 16);
  int cfB = blockIdx.y * NF;
  int rowBaseOut = ogr0 + tileR * 4;
  int rowBase = rowBaseOut - 1;
  int colBase = tileC * 32;

  f32x4 acc[2][NF];
#pragma unroll
  for (int mf = 0; mf < 2; ++mf)
#pragma unroll
    for (int nf = 0; nf < NF; ++nf) acc[mf][nf] = zero4();

  f16x8 stv[4];        // UP=0 staged values
  f16x8 stc[4][4];     // UP=1 staged corners

  auto prefetch = [&](int cs) {
#pragma unroll
    for (int k = 0; k < 4; ++k) {
      int u = tid + k * 256;
      if (u < 816) {
        int s = u & 3;
        int pxy = u >> 2;
        int x = pxy % 34, y = pxy / 34;
        int gy = rowBase + y, gx = colBase + x - 1;
        if (UP) {
          stc[k][0] = zero8(); stc[k][1] = zero8();
          stc[k][2] = zero8(); stc[k][3] = zero8();
          if (gy >= 0 && gy < Ht && gx >= 0 && gx < Wd) {
            float uy = ((float)gy + 0.5f) * 0.25f - 0.5f;
            uy = fminf(fmaxf(uy, 0.f), (float)(FH - 1));
            int y0 = (int)floorf(uy);
            int y1 = min(y0 + 1, FH - 1);
            float ux = ((float)gx + 0.5f) * 0.25f - 0.5f;
            ux = fminf(fmaxf(ux, 0.f), (float)(FW - 1));
            int x0 = (int)floorf(ux);
            int x1 = min(x0 + 1, FW - 1);
            const f16* xb = Xin + (size_t)b * HWl * 128 + cs * 32 + s * 8;
            stc[k][0] = *(const f16x8*)&xb[(size_t)(y0 * FW + x0) * 128];
            stc[k][1] = *(const f16x8*)&xb[(size_t)(y0 * FW + x1) * 128];
            stc[k][2] = *(const f16x8*)&xb[(size_t)(y1 * FW + x0) * 128];
            stc[k][3] = *(const f16x8*)&xb[(size_t)(y1 * FW + x1) * 128];
          }
        } else {
          stv[k] = zero8();
          if (gy >= in_r0 && gy < in_r0 + in_rows && gx >= 0 && gx < Wd)
            stv[k] = *(const f16x8*)&Xin[(((size_t)b * in_rows + (gy - in_r0)) * Wd + gx) * Cs_in
                                         + cs * 32 + s * 8];
        }
      }
    }
  };

  auto writeLDS = [&]() {
#pragma unroll
    for (int k = 0; k < 4; ++k) {
      int u = tid + k * 256;
      if (u < 816) {
        int s = u & 3;
        int pxy = u >> 2;
        f16x8 v;
        if (UP) {
          int x = pxy % 34, y = pxy / 34;
          int gy = rowBase + y, gx = colBase + x - 1;
          float uy = ((float)gy + 0.5f) * 0.25f - 0.5f;
          uy = fminf(fmaxf(uy, 0.f), (float)(FH - 1));
          float fy = uy - floorf(uy);
          float ux = ((float)gx + 0.5f) * 0.25f - 0.5f;
          ux = fminf(fmaxf(ux, 0.f), (float)(FW - 1));
          float fx = ux - floorf(ux);
#pragma unroll
          for (int jj = 0; jj < 8; ++jj) {
            float t0 = (float)stc[k][0][jj] * (1.f - fx) + (float)stc[k][1][jj] * fx;
            float t1 = (float)stc[k][2][jj] * (1.f - fx) + (float)stc[k][3][jj] * fx;
            v[jj] = (f16)(t0 * (1.f - fy) + t1 * fy);
          }
        } else {
          v = stv[k];
        }
        *(f16x8*)((char*)sA + pxy * 80 + s * 16) = v;
      }
    }
  };

  prefetch(0);
  for (int cs = 0; cs < KS; ++cs) {
    writeLDS();
    __syncthreads();
    if (cs + 1 < KS) prefetch(cs + 1);   // latency hides under MFMA phase
#pragma unroll
    for (int ky = 0; ky < 3; ++ky) {
#pragma unroll
      for (int kx = 0; kx < 3; ++kx) {
        const char* ab = (const char*)sA;
        f16x8 a0 = *(const f16x8*)(ab + ((wv + ky) * 34 + l15 + kx) * 80 + l4 * 16);
        f16x8 a1 = *(const f16x8*)(ab + ((wv + ky) * 34 + l15 + 16 + kx) * 80 + l4 * 16);
        int tap = ky * 3 + kx;
#pragma unroll
        for (int nf = 0; nf < NF; ++nf) {
          f16x8 bf = *(const f16x8*)&Wf[((((size_t)tap * KS + cs) * CoF + cfB + nf) * 64 + lane) * 8];
          acc[0][nf] = __builtin_amdgcn_mfma_f32_16x16x32_f16(a0, bf, acc[0][nf], 0, 0, 0);
          acc[1][nf] = __builtin_amdgcn_mfma_f32_16x16x32_f16(a1, bf, acc[1][nf], 0, 0, 0);
        }
      }
    }
    __syncthreads();
  }

  int r = rowBaseOut + wv;
  if (r < ogr1) {
    size_t rowoff = ((size_t)b * out_rows + (r - out_r0)) * Wd;
#pragma unroll
    for (int nf = 0; nf < NF; ++nf) {
      int co = co0 + nf * 16 + l15;
      float bv = bias[co];
#pragma unroll
      for (int mf = 0; mf < 2; ++mf) {
        int xo = colBase + mf * 16 + l4 * 4;
#pragma unroll
        for (int rg = 0; rg < 4; ++rg) {
          float v = activ<ACT>(acc[mf][nf][rg] + bv);
          Out[(rowoff + xo + rg) * Cs_out + co] = (f16)v;
        }
      }
    }
  }
}

// ---------------------------------------------------------------------------
// MFMA 1x1 conv (pure GEMM, no LDS). Wave = 32px x up-to-64co tile.
// ---------------------------------------------------------------------------
template<int ACT, int RES>
__global__ __launch_bounds__(256) void k_gemm1x1(
    const f16* __restrict__ X, const f16* __restrict__ Wf,
    const float* __restrict__ bias, f16* __restrict__ Out,
    int KS, int CoF, int Cs_in, int Cs_out, int Cr, int coTiles, int pixTiles)
{
  int wid = blockIdx.x * 4 + (threadIdx.x >> 6);
  int lane = threadIdx.x & 63;
  int total = pixTiles * coTiles;
  if (wid >= total) return;
  int coT = wid % coTiles;
  int pixT = wid / coTiles;
  int nfc = min(4, CoF - coT * 4);
  int l15 = lane & 15, l4 = lane >> 4;

  f32x4 acc[2][4];
#pragma unroll
  for (int mf = 0; mf < 2; ++mf)
#pragma unroll
    for (int nf = 0; nf < 4; ++nf) acc[mf][nf] = zero4();

  int pA0 = pixT * 32 + l15;
  for (int ks = 0; ks < KS; ++ks) {
    f16x8 a0 = *(const f16x8*)&X[(size_t)pA0 * Cs_in + ks * 32 + l4 * 8];
    f16x8 a1 = *(const f16x8*)&X[(size_t)(pA0 + 16) * Cs_in + ks * 32 + l4 * 8];
#pragma unroll
    for (int nf = 0; nf < 4; ++nf) {
      if (nf < nfc) {
        f16x8 bf = *(const f16x8*)&Wf[(((size_t)ks * CoF + coT * 4 + nf) * 64 + lane) * 8];
        acc[0][nf] = __builtin_amdgcn_mfma_f32_16x16x32_f16(a0, bf, acc[0][nf], 0, 0, 0);
        acc[1][nf] = __builtin_amdgcn_mfma_f32_16x16x32_f16(a1, bf, acc[1][nf], 0, 0, 0);
      }
    }
  }
#pragma unroll
  for (int nf = 0; nf < 4; ++nf) {
    if (nf < nfc) {
      int co = coT * 64 + nf * 16 + l15;
      if (co < Cr) {
        float bv = bias[co];
#pragma unroll
        for (int mf = 0; mf < 2; ++mf) {
          int p0 = pixT * 32 + mf * 16 + l4 * 4;
#pragma unroll
          for (int rg = 0; rg < 4; ++rg) {
            float v = activ<ACT>(acc[mf][nf][rg] + bv);
            size_t o = (size_t)(p0 + rg) * Cs_out + co;
            if (RES) v += (float)Out[o];
            Out[o] = (f16)v;
          }
        }
      }
    }
  }
}

// ---------------------------------------------------------------------------
// GroupNorm on NHWC f16, two stage.
// ---------------------------------------------------------------------------
__global__ __launch_bounds__(256) void k_gn_part_h(
    const f16* __restrict__ X, float* __restrict__ part)
{
  int s = blockIdx.x & 7;
  int g = (blockIdx.x >> 3) & 7;
  int b = blockIdx.x >> 6;
  int tid = threadIdx.x;
  const f16* Xp = X + (size_t)b * HWl * 128 + g * 16 + (tid & 1) * 8;
  float sum = 0.f, ss = 0.f;
  for (int p = s * 1920 + (tid >> 1); p < (s + 1) * 1920; p += 128) {
    f16x8 v = *(const f16x8*)&Xp[(size_t)p * 128];
#pragma unroll
    for (int jj = 0; jj < 8; ++jj) { float f = (float)v[jj]; sum += f; ss += f * f; }
  }
  __shared__ float sh1[256], sh2[256];
  sh1[tid] = sum; sh2[tid] = ss;
  __syncthreads();
  for (int st = 128; st > 0; st >>= 1) {
    if (tid < st) { sh1[tid] += sh1[tid + st]; sh2[tid] += sh2[tid + st]; }
    __syncthreads();
  }
  if (tid == 0) {
    part[((b * 8 + g) * 8 + s) * 2] = sh1[0];
    part[((b * 8 + g) * 8 + s) * 2 + 1] = sh2[0];
  }
}

__global__ __launch_bounds__(256) void k_gn_apply_h(
    const f16* __restrict__ X, const float* __restrict__ gw,
    const float* __restrict__ gb, const float* __restrict__ part,
    f16* __restrict__ Q)
{
  int idx = blockIdx.x * blockDim.x + threadIdx.x;
  int total = Bn * HWl * 16;
  if (idx >= total) return;
  int u = idx & 15;
  int pix = (idx >> 4) % HWl;
  int b = idx / (16 * HWl);
  int c0 = u * 8;
  int g = c0 >> 4;
  const float* pp = part + ((b * 8 + g) * 8) * 2;
  float sum = 0.f, ss = 0.f;
#pragma unroll
  for (int s = 0; s < 8; ++s) { sum += pp[s * 2]; ss += pp[s * 2 + 1]; }
  const float n = 16.f * HWl;
  float mean = sum / n;
  float var = ss / n - mean * mean;
  float inv = rsqrtf(var + 1e-5f);
  f16x8 v = *(const f16x8*)&X[((size_t)b * HWl + pix) * 128 + c0];
  f16x8 r;
#pragma unroll
  for (int jj = 0; jj < 8; ++jj) {
    int c = c0 + jj;
    r[jj] = (f16)(((float)v[jj] - mean) * (gw[c] * inv) + gb[c]);
  }
  *(f16x8*)&Q[((size_t)b * HWl + pix) * 128 + c0] = r;
}

// softmax over the 9 points; attn NHWC [b][pix][48], heads at c = head*9
__global__ __launch_bounds__(256) void k_softmax9_h(f16* __restrict__ a)
{
  int idx = blockIdx.x * blockDim.x + threadIdx.x;
  if (idx >= Bn * NHd * HWl) return;
  int pix = idx % HWl;
  int head = (idx / HWl) & 3;
  int b = idx / (HWl * NHd);
  f16* base = a + ((size_t)b * HWl + pix) * 48 + head * 9;
  float v[9];
  float m = -1e30f;
#pragma unroll
  for (int p0 = 0; p0 < 9; ++p0) { v[p0] = (float)base[p0]; m = fmaxf(m, v[p0]); }
  float s = 0.f;
#pragma unroll
  for (int p0 = 0; p0 < 9; ++p0) { v[p0] = expf(v[p0] - m); s += v[p0]; }
  float inv = 1.f / s;
#pragma unroll
  for (int p0 = 0; p0 < 9; ++p0) base[p0] = (f16)(v[p0] * inv);
}

// ---------------------------------------------------------------------------
// Deformable sampling, all NHWC. Thread per (b, head, pix), 32 head-channels.
// ---------------------------------------------------------------------------
__global__ __launch_bounds__(256) void k_deform_h(
    const f16* __restrict__ vals, const f16* __restrict__ off,
    const f16* __restrict__ attn, f16* __restrict__ outa)
{
  int idx = blockIdx.x * blockDim.x + threadIdx.x;
  if (idx >= Bn * NHd * HWl) return;
  int pix = idx % HWl;
  int head = (idx / HWl) & 3;
  int b = idx / (HWl * NHd);
  int j = pix % FW, i = pix / FW;

  const float kx = (float)FW / (float)(FW - 1);
  const float ky = (float)FH / (float)(FH - 1);
  const f16* vb = vals + (size_t)b * HWl * 128 + head * 32;
  const f16* ab = attn + ((size_t)b * HWl + pix) * 48 + head * 9;
  const f16* ob = off + ((size_t)b * HWl + pix) * 80 + head * 18;

  float acc[32];
#pragma unroll
  for (int k = 0; k < 32; ++k) acc[k] = 0.f;

#pragma unroll
  for (int p0 = 0; p0 < 9; ++p0) {
    float ox = (float)ob[p0 * 2];
    float oy = (float)ob[p0 * 2 + 1];
    float aw = (float)ab[p0];
    float xf = ((float)j + ox) * kx - 0.5f;
    float yf = ((float)i + oy) * ky - 0.5f;
    xf = fminf(fmaxf(xf, 0.f), (float)(FW - 1));
    yf = fminf(fmaxf(yf, 0.f), (float)(FH - 1));
    int x0 = (int)floorf(xf), y0 = (int)floorf(yf);
    int x1 = min(x0 + 1, FW - 1), y1 = min(y0 + 1, FH - 1);
    float fx = xf - (float)x0, fy = yf - (float)y0;
    float w00 = aw * (1.f - fx) * (1.f - fy);
    float w01 = aw * fx * (1.f - fy);
    float w10 = aw * (1.f - fx) * fy;
    float w11 = aw * fx * fy;
    const f16x8* c00 = (const f16x8*)&vb[(size_t)(y0 * FW + x0) * 128];
    const f16x8* c01 = (const f16x8*)&vb[(size_t)(y0 * FW + x1) * 128];
    const f16x8* c10 = (const f16x8*)&vb[(size_t)(y1 * FW + x0) * 128];
    const f16x8* c11 = (const f16x8*)&vb[(size_t)(y1 * FW + x1) * 128];
#pragma unroll
    for (int k8 = 0; k8 < 4; ++k8) {
      f16x8 a = c00[k8], bb = c01[k8], cc = c10[k8], dd = c11[k8];
#pragma unroll
      for (int jj = 0; jj < 8; ++jj)
        acc[k8 * 8 + jj] += w00 * (float)a[jj] + w01 * (float)bb[jj]
                          + w10 * (float)cc[jj] + w11 * (float)dd[jj];
    }
  }
  f16* op = outa + ((size_t)b * HWl + pix) * 128 + head * 32;
#pragma unroll
  for (int k = 0; k < 32; ++k) op[k] = (f16)acc[k];
}

// ---------------------------------------------------------------------------
// dec2: 32->3 direct conv from NHWC f16 window rows [b0,b0+brows) + sigmoid,
// writes NCHW f32 output rows [c0, c0+R).
// ---------------------------------------------------------------------------
__global__ __launch_bounds__(256) void k_dec2_h(
    const f16* __restrict__ Xb, const float* __restrict__ w,
    const float* __restrict__ bias, float* __restrict__ out,
    int c0, int b0, int brows, int R)
{
  int idx = blockIdx.x * blockDim.x + threadIdx.x;
  if (idx >= Bn * R * Wh) return;
  int x = idx % Wh;
  int y = c0 + (idx / Wh) % R;
  int b = idx / (Wh * R);
  float a0 = bias[0], a1 = bias[1], a2 = bias[2];
#pragma unroll
  for (int ky = 0; ky < 3; ++ky) {
    int gy = y + ky - 1;
    if (gy < 0 || gy >= Hh) continue;
#pragma unroll
    for (int kxx = 0; kxx < 3; ++kxx) {
      int gx = x + kxx - 1;
      if (gx < 0 || gx >= Wh) continue;
      int tap = ky * 3 + kxx;
      const f16* px = Xb + ((size_t)(b * brows + (gy - b0)) * Wh + gx) * 32;
#pragma unroll
      for (int k8 = 0; k8 < 4; ++k8) {
        f16x8 v = *(const f16x8*)&px[k8 * 8];
#pragma unroll
        for (int jj = 0; jj < 8; ++jj) {
          int ci = k8 * 8 + jj;
          float f = (float)v[jj];
          a0 += f * w[(0 * 32 + ci) * 9 + tap];
          a1 += f * w[(1 * 32 + ci) * 9 + tap];
          a2 += f * w[(2 * 32 + ci) * 9 + tap];
        }
      }
    }
  }
  size_t o = ((size_t)(b * 3 + 0) * Hh + y) * Wh + x;
  out[o] = 1.f / (1.f + expf(-a0));
  out[o + (size_t)Hh * Wh] = 1.f / (1.f + expf(-a1));
  out[o + (size_t)2 * Hh * Wh] = 1.f / (1.f + expf(-a2));
}

// ---------------------------------------------------------------------------
extern "C" void kernel_launch(void* const* d_in, const int* in_sizes, int n_in,
                              void* d_out, int out_size, void* d_ws, size_t ws_size,
                              hipStream_t stream) {
  (void)in_sizes; (void)n_in; (void)out_size; (void)ws_size;
  const float* feat1  = (const float*)d_in[0];
  const float* feat2  = (const float*)d_in[1];
  const float* flowf  = (const float*)d_in[2];
  const float* flowb  = (const float*)d_in[3];
  const float* edge1  = (const float*)d_in[4];
  const float* edge2  = (const float*)d_in[5];
  const float* fuse_w0 = (const float*)d_in[6];
  const float* fuse_b0 = (const float*)d_in[7];
  const float* fuse_w1 = (const float*)d_in[8];
  const float* fuse_b1 = (const float*)d_in[9];
  const float* gn_g   = (const float*)d_in[10];
  const float* gn_b   = (const float*)d_in[11];
  const float* off_w0 = (const float*)d_in[12];
  const float* off_b0 = (const float*)d_in[13];
  const float* off_w1 = (const float*)d_in[14];
  const float* off_b1 = (const float*)d_in[15];
  const float* aw_w0  = (const float*)d_in[16];
  const float* aw_b0  = (const float*)d_in[17];
  const float* aw_w1  = (const float*)d_in[18];
  const float* aw_b1  = (const float*)d_in[19];
  const float* val_w  = (const float*)d_in[20];
  const float* val_b  = (const float*)d_in[21];
  const float* out_w  = (const float*)d_in[22];
  const float* out_b  = (const float*)d_in[23];
  const float* ffn_w0 = (const float*)d_in[24];
  const float* ffn_b0 = (const float*)d_in[25];
  const float* ffn_w1 = (const float*)d_in[26];
  const float* ffn_b1 = (const float*)d_in[27];
  const float* dec_w0 = (const float*)d_in[28];
  const float* dec_b0 = (const float*)d_in[29];
  const float* dec_w1 = (const float*)d_in[30];
  const float* dec_b1 = (const float*)d_in[31];
  const float* dec_w2 = (const float*)d_in[32];
  const float* dec_b2 = (const float*)d_in[33];
  float* out = (float*)d_out;

  // ---- workspace layout (f16 units), ~80 MB total ----
  f16* ws16 = (f16*)d_ws;
  size_t o = 0;
  auto alloc = [&](size_t n) { f16* p = ws16 + o; o += (n + 7) & ~(size_t)7; return p; };
  f16* xbuf  = alloc((size_t)2 * HWl * 128);
  f16* pool  = alloc((size_t)0);               // pool start marker
  f16* regA  = alloc((size_t)2 * HWl * 288);   // fused / t_off / t_aw / ffn_t
  f16* regB  = alloc((size_t)2 * HWl * 128);   // source / out_attn
  f16* regC  = alloc((size_t)2 * HWl * 128);   // fuse0-out / qb
  f16* offb  = alloc((size_t)2 * HWl * 80);
  f16* attnb = alloc((size_t)2 * HWl * 48);
  f16* regF  = alloc((size_t)2 * HWl * 131);   // valsb (+ slack)
  f16* featT1 = alloc((size_t)2 * HWl * 128);
  f16* featT2 = alloc((size_t)2 * HWl * 128);
  f16* wfF0 = alloc(9 * 288 * 128);
  f16* wfF1 = alloc(9 * 128 * 128);
  f16* wfO0 = alloc(9 * 128 * 128);
  f16* wfA0 = alloc(9 * 128 * 128);
  f16* wfD0 = alloc(9 * 128 * 64);
  f16* wfD1 = alloc(9 * 64 * 32);
  f16* w1O  = alloc(4 * 5 * 512);
  f16* w1A  = alloc(4 * 3 * 512);
  f16* w1V  = alloc(4 * 8 * 512);
  f16* w1U  = alloc(4 * 8 * 512);
  f16* w1G0 = alloc(4 * 16 * 512);
  f16* w1G1 = alloc(8 * 8 * 512);
  float* gnp = (float*)alloc(512);             // 256 f32 partials

  f16* fused = regA;
  f16* t_off = regA;
  f16* t_aw  = regA;
  f16* ffn_t = regA;
  f16* src_h = regB;
  f16* out_attn = regB;
  f16* tmp_h = regC;
  f16* qb    = regC;
  f16* valsb = regF;
  // Decoder overlays the whole pool (dead after FFN):
  // bufA: 2*196*640*64 = 16,056,320 ; bufB: 2*194*640*32 = 7,946,240
  // pool size = 24,657,920+ f16 -> fits.
  f16* bufA  = pool;
  f16* bufB  = pool + (size_t)2 * 196 * 640 * 64;

  dim3 blk(256);
  auto pg = [](long n) { return dim3((unsigned)((n + 255) / 256)); };

  // ---- merged weight prep (12 jobs, 1 launch) ----
  PrepArgs pa;
  int pb = 0;
  auto addj = [&](int k, const float* w, f16* wf, int Cout, int cing, int coutg,
                  int KS, int CoF, int taps) {
    pa.j[k] = PrepJob{w, wf, Cout, cing, coutg, KS, CoF, taps, pb};
    pb += (taps * KS * CoF * 64 + 255) / 256;
  };
  addj(0, fuse_w0, wfF0, 128, 259, 128, 9, 8, 9);
  addj(1, fuse_w1, wfF1, 128, 128, 128, 4, 8, 9);
  addj(2, off_w0, wfO0, 128, 32, 32, 4, 8, 9);
  addj(3, aw_w0,  wfA0, 128, 32, 32, 4, 8, 9);
  addj(4, dec_w0, wfD0, 64, 128, 64, 4, 4, 9);
  addj(5, dec_w1, wfD1, 32, 64, 32, 2, 2, 9);
  addj(6, off_w1, w1O, 72, 128, 128, 4, 5, 1);
  addj(7, aw_w1,  w1A, 36, 128, 128, 4, 3, 1);
  addj(8, val_w,  w1V, 128, 128, 128, 4, 8, 1);
  addj(9, out_w,  w1U, 128, 128, 128, 4, 8, 1);
  addj(10, ffn_w0, w1G0, 256, 128, 128, 4, 16, 1);
  addj(11, ffn_w1, w1G1, 128, 256, 256, 8, 8, 1);
  // fix 1x1 cin_g/cout_g semantics: cin_g=Cin, cout_g=Cout (band=0)
  pa.j[6].cin_g = 128;  pa.j[6].cout_g = 72;
  pa.j[7].cin_g = 128;  pa.j[7].cout_g = 36;
  pa.j[8].cin_g = 128;  pa.j[8].cout_g = 128;
  pa.j[9].cin_g = 128;  pa.j[9].cout_g = 128;
  pa.j[10].cin_g = 128; pa.j[10].cout_g = 256;
  pa.j[11].cin_g = 256; pa.j[11].cout_g = 128;
  k_wprep_all<<<dim3((unsigned)pb), blk, 0, stream>>>(pa);

  // ---- 0. feats -> NHWC f16 ----
  k_tr_h<<<pg(2L * Bn * HWl * 8), blk, 0, stream>>>(feat1, feat2, featT1, featT2);
  // ---- 1. warp + concat + source ----
  k_warp_fuse_h<<<pg((long)Bn * HWl * 8), blk, 0, stream>>>(featT1, featT2, flowf, flowb,
                                                            edge1, edge2, fused, src_h);
  // ---- 2-3. fuse convs ----
  dim3 gF(24 * 5, 2, 2);
  k_conv3m<1, 0, 4><<<gF, blk, 0, stream>>>(fused, wfF0, fuse_b0, tmp_h,
      9, 8, 288, 128, FW, FH, 0, FH, 0, FH, 0, FH);
  k_conv3m<1, 0, 4><<<gF, blk, 0, stream>>>(tmp_h, wfF1, fuse_b1, xbuf,
      4, 8, 128, 128, FW, FH, 0, FH, 0, FH, 0, FH);
  // ---- 4. group norm ----
  k_gn_part_h<<<dim3(128), blk, 0, stream>>>(xbuf, gnp);
  k_gn_apply_h<<<pg(2L * HWl * 16), blk, 0, stream>>>(xbuf, gn_g, gn_b, gnp, qb);
  // ---- 5-6. offsets ----
  k_conv3m<1, 0, 4><<<gF, blk, 0, stream>>>(qb, wfO0, off_b0, t_off,
      4, 8, 128, 128, FW, FH, 0, FH, 0, FH, 0, FH);
  k_gemm1x1<0, 0><<<dim3(480), blk, 0, stream>>>(t_off, w1O, off_b1, offb,
      4, 5, 128, 80, 72, 2, 960);
  // ---- 7-8. attention weights + softmax ----
  k_conv3m<1, 0, 4><<<gF, blk, 0, stream>>>(qb, wfA0, aw_b0, t_aw,
      4, 8, 128, 128, FW, FH, 0, FH, 0, FH, 0, FH);
  k_gemm1x1<0, 0><<<dim3(240), blk, 0, stream>>>(t_aw, w1A, aw_b1, attnb,
      4, 3, 128, 48, 36, 1, 960);
  k_softmax9_h<<<pg(2L * NHd * HWl), blk, 0, stream>>>(attnb);
  // ---- 9. vals ----
  k_gemm1x1<0, 0><<<dim3(480), blk, 0, stream>>>(src_h, w1V, val_b, valsb,
      4, 8, 128, 128, 128, 2, 960);
  // ---- 10. deform ----
  k_deform_h<<<pg(2L * NHd * HWl), blk, 0, stream>>>(valsb, offb, attnb, out_attn);
  // ---- 11. out-proj (residual into xbuf) ----
  k_gemm1x1<0, 1><<<dim3(480), blk, 0, stream>>>(out_attn, w1U, out_b, xbuf,
      4, 8, 128, 128, 128, 2, 960);
  // ---- 12-13. FFN ----
  k_gemm1x1<2, 0><<<dim3(960), blk, 0, stream>>>(xbuf, w1G0, ffn_b0, ffn_t,
      4, 16, 128, 256, 256, 4, 960);
  k_gemm1x1<0, 1><<<dim3(480), blk, 0, stream>>>(ffn_t, w1G1, ffn_b1, xbuf,
      8, 8, 256, 128, 128, 2, 960);

  // ---- 14. decoder, 2 chunks of 192 rows; upsample fused into dec0 staging ----
  for (int c0 = 0; c0 < Hh; c0 += 192) {
    int c1 = c0 + 192;
    int a0 = c0 - 2 > 0 ? c0 - 2 : 0;
    int a1 = c1 + 2 < Hh ? c1 + 2 : Hh;
    int b0 = c0 - 1 > 0 ? c0 - 1 : 0;
    int b1 = c1 + 1 < Hh ? c1 + 1 : Hh;
    int ar = a1 - a0, br = b1 - b0;
    dim3 gD0((unsigned)(((ar + 3) / 4) * 20), 1, 2);
    k_conv3m<1, 1, 4><<<gD0, blk, 0, stream>>>(xbuf, wfD0, dec_b0, bufA,
        4, 4, 128, 64, Wh, Hh, 0, 0, a0, ar, a0, a1);
    dim3 gD1((unsigned)(((br + 3) / 4) * 20), 1, 2);
    k_conv3m<1, 0, 2><<<gD1, blk, 0, stream>>>(bufA, wfD1, dec_b1, bufB,
        2, 2, 64, 32, Wh, Hh, a0, ar, b0, br, b0, b1);
    k_dec2_h<<<pg(2L * 192 * Wh), blk, 0, stream>>>(bufB, dec_w2, dec_b2, out,
                                                    c0, b0, br, 192);
  }
}